// Round 15
// baseline (1494.808 us; speedup 1.0000x reference)
//
#include <hip/hip_runtime.h>
#include <cmath>

#define Dm   512
#define Hn   8
#define Ln   6
#define DFFm 2048
#define Vm   32000
#define Bn   2
#define Sn   1024
#define DHm  64
#define Mrows (Bn*Sn)   // 2048

typedef unsigned short ushort_t;
typedef __attribute__((ext_vector_type(8))) short          s16x8;
typedef __attribute__((ext_vector_type(8))) unsigned short u16x8;
typedef __attribute__((ext_vector_type(4))) float          f32x4;

__device__ __forceinline__ ushort_t f2bf(float x) {
    union { float f; unsigned u; } un; un.f = x;
    unsigned r = un.u + 0x7fffu + ((un.u >> 16) & 1u);
    return (ushort_t)(r >> 16);
}

// ---------------------------------------------------------------------------
// Stage TR rows x 64 k of bf16 from global into a swizzled LDS tile,
// cooperatively across NW waves (T2 swizzle via pre-swizzled source;
// global_load_lds writes linearly).
// ---------------------------------------------------------------------------
template<int TR, int NW>
__device__ __forceinline__ void stage_tile(const ushort_t* __restrict__ src, int ld,
                                           ushort_t* lds, int k0, int w, int lane)
{
    constexpr int CH = TR / (8 * NW);           // row-chunks per wave
    #pragma unroll
    for (int c = 0; c < CH; ++c) {
        const int rb = (w * CH + c) * 8;        // wave-uniform row base
        const int r  = rb + (lane >> 3);
        const ushort_t* gp = src + (size_t)r * ld + k0
                           + (((lane & 7) ^ ((lane >> 3) & 7)) << 3);
        __builtin_amdgcn_global_load_lds(
            (const __attribute__((address_space(1))) void*)gp,
            (__attribute__((address_space(3))) void*)(lds + rb * 64),
            16, 0, 0);
    }
}

// read 8 bf16: LDS tile row r, logical 16B-slot st (0..7)
__device__ __forceinline__ s16x8 ldrd(const ushort_t* lds, int r, int st)
{
    return *(const s16x8*)&lds[r * 64 + ((st ^ (r & 7)) << 3)];
}

// ---------------------------------------------------------------------------
// bf16 MFMA GEMM: C[M,N] = A[M,K] @ Bt[N,K]^T  (+bias) (+relu)
// Double-buffered LDS, 1-deep prefetch, one barrier per K-step.
// NW = waves/block (TLP lever): 4 -> 2x2 wave grid; 8 -> 2x4 (512 threads).
// Split-K usage: grid.z=2 with nh=1, A_sb=B_sb=K_half (element offset into
//   the K dim), C_sb = partial-buffer stride, K=K_half. Bias applied only by
//   blockIdx.z==0 (gate invariant for non-split calls).
// VTOUT: cols in [voff, voff+512) are written transposed to
//   (VTp + z*VT_sz)[zz][d][s]; other cols fall through to row-major C.
// SWZ (fc only): XCD-aware bijective remap (weight panels HBM-fetched once).
// ---------------------------------------------------------------------------
template<int TM, int TN, int NW, bool OBF, bool BIAS, bool RELU, bool VTOUT, bool SWZ>
__global__ __launch_bounds__(NW * 64) void gemm_bf(
    const ushort_t* __restrict__ A, const ushort_t* __restrict__ Bt,
    void* __restrict__ Cv, const float* __restrict__ bias,
    int K, int lda, int ldb, int ldc,
    long A_sb, long A_sh, long B_sb, long B_sh, long C_sb, long C_sh, int nh,
    ushort_t* __restrict__ VTp, int voff, long VT_sz)
{
    constexpr int WC = NW / 2;                  // wave-grid cols (2 or 4)
    constexpr int FI = TM / 32;                 // frags per wave, M dir
    constexpr int FJ = TN / (16 * WC);          // frags per wave, N dir
    __shared__ __align__(16) ushort_t As[2][TM * 64];
    __shared__ __align__(16) ushort_t Bs[2][TN * 64];

    const int z = blockIdx.z, b = z / nh, h = z - b * nh;
    A  += (size_t)b * A_sb + (size_t)h * A_sh;
    Bt += (size_t)b * B_sb + (size_t)h * B_sh;
    ushort_t* VTl = VTp + (size_t)z * VT_sz;

    int bx = blockIdx.x, by = blockIdx.y;
    if constexpr (SWZ) {
        const int ncol = gridDim.x, nrow = gridDim.y;
        const int total = ncol * nrow;
        const int flat = bx + by * ncol;          // dispatch order (x fastest)
        const int per = total >> 3;
        const int g = (flat & 7) * per + (flat >> 3);
        bx = g / nrow;
        by = g - bx * nrow;
    }

    const int tid  = threadIdx.x;
    const int w    = tid >> 6, lane = tid & 63;
    const int m0   = by * TM, n0 = bx * TN;
    const int rw   = (w / WC) * (TM / 2);       // wave sub-tile row base
    const int cn   = (w % WC) * (TN / WC);      // wave sub-tile col base
    const int l15  = lane & 15, l4 = lane >> 4;

    const ushort_t* Ab = A + (size_t)m0 * lda;
    const ushort_t* Bb = Bt + (size_t)n0 * ldb;

    f32x4 acc[FI][FJ] = {};

    stage_tile<TM, NW>(Ab, lda, As[0], 0, w, lane);
    stage_tile<TN, NW>(Bb, ldb, Bs[0], 0, w, lane);
    __syncthreads();

    const int nk = K >> 6;
    for (int t = 0; t < nk; ++t) {
        const int cur = t & 1;
        if (t + 1 < nk) {
            stage_tile<TM, NW>(Ab, lda, As[cur ^ 1], (t + 1) << 6, w, lane);
            stage_tile<TN, NW>(Bb, ldb, Bs[cur ^ 1], (t + 1) << 6, w, lane);
        }
        #pragma unroll
        for (int ks = 0; ks < 2; ++ks) {
            const int st = ks * 4 + l4;
            s16x8 av[FI], bv[FJ];
            #pragma unroll
            for (int i = 0; i < FI; ++i) av[i] = ldrd(As[cur], rw + i * 16 + l15, st);
            #pragma unroll
            for (int j = 0; j < FJ; ++j) bv[j] = ldrd(Bs[cur], cn + j * 16 + l15, st);
            #pragma unroll
            for (int i = 0; i < FI; ++i)
                #pragma unroll
                for (int j = 0; j < FJ; ++j)
                    acc[i][j] = __builtin_amdgcn_mfma_f32_16x16x32_bf16(
                                    av[i], bv[j], acc[i][j], 0, 0, 0);
        }
        __syncthreads();
    }

    // epilogue: D[col=lane&15, row=(lane>>4)*4 + r]  (m89-verified layout)
    const int colb = n0 + cn + l15;
    const int rowb = m0 + rw + (l4 << 2);
    const bool doBias = BIAS && (blockIdx.z == 0);
    float bvv[FJ];
    #pragma unroll
    for (int j = 0; j < FJ; ++j) bvv[j] = doBias ? bias[colb + j * 16] : 0.f;

    if constexpr (OBF) {
        ushort_t* C = (ushort_t*)Cv + (size_t)b * C_sb + (size_t)h * C_sh;
        #pragma unroll
        for (int i = 0; i < FI; ++i)
            #pragma unroll
            for (int r = 0; r < 4; ++r) {
                const int row = rowb + i * 16 + r;
                #pragma unroll
                for (int j = 0; j < FJ; ++j) {
                    float v = acc[i][j][r] + bvv[j];
                    if (RELU) v = fmaxf(v, 0.f);
                    const int col = colb + j * 16;
                    if (VTOUT && col >= voff && col < voff + 512) {
                        const int hc = (col - voff) >> 6, d = (col - voff) & 63;
                        const int zz = (row >> 10) * 8 + hc;
                        VTl[(size_t)zz * (64 * Sn) + (size_t)d * Sn + (row & (Sn - 1))] = f2bf(v);
                    } else {
                        C[(size_t)row * ldc + col] = f2bf(v);
                    }
                }
            }
    } else {
        float* C = (float*)Cv + (size_t)b * C_sb + (size_t)h * C_sh;
        #pragma unroll
        for (int i = 0; i < FI; ++i)
            #pragma unroll
            for (int r = 0; r < 4; ++r) {
                const size_t row = rowb + i * 16 + r;
                #pragma unroll
                for (int j = 0; j < FJ; ++j) {
                    float v = acc[i][j][r] + bvv[j];
                    if (RELU) v = fmaxf(v, 0.f);
                    C[row * ldc + colb + j * 16] = v;
                }
            }
    }
}

// ---------------------------------------------------------------------------
// Flash-fused attention, KV-split across 2 wave groups (8 waves, 512 thr).
// MODE 0: pad mask; MODE 1: causal. (See round-10 notes.)
// ---------------------------------------------------------------------------
template<int MODE>
__global__ __launch_bounds__(512) void flash_attn(
    const ushort_t* __restrict__ Qp, const ushort_t* __restrict__ Kp,
    const ushort_t* __restrict__ VTp, ushort_t* __restrict__ AO,
    const int* __restrict__ tok, int ldq, int ldk)
{
    __shared__ __align__(16) ushort_t Ks[2][2][64 * 64];   // [group][buf]
    __shared__ __align__(16) ushort_t Vs[2][2][64 * 64];
    __shared__ __align__(16) ushort_t Ps[8][16 * 64];
    __shared__ float msk[Sn];
    __shared__ float mrg[4][64][25];   // group-1 partials: 16 o + 4 m + 4 l

    const int z = blockIdx.y, b = z >> 3, h = z & 7;
    const int qb = blockIdx.x * 64;
    const int tid = threadIdx.x, w = tid >> 6, lane = tid & 63;
    const int g = w >> 2, w4 = w & 3;
    const int l15 = lane & 15, l4 = lane >> 4;

    const ushort_t* Qbase = Qp + (size_t)b * Sn * ldq + h * 64;
    const ushort_t* Kbase = Kp + (size_t)b * Sn * ldk + h * 64;
    const ushort_t* Vbase = VTp + (size_t)z * 64 * Sn;
    ushort_t* Obase = AO + ((size_t)(b * Sn + qb)) * Dm + h * 64;

    if (MODE == 0) {
        const int* tb = tok + (size_t)b * Sn;
        for (int i = tid; i < Sn; i += 512) msk[i] = (tb[i] == 0) ? 1.f : 0.f;
    }

    const int qrow = qb + w4 * 16 + l15;
    s16x8 qv[2];
    qv[0] = *(const s16x8*)(Qbase + (size_t)qrow * ldq + l4 * 8);
    qv[1] = *(const s16x8*)(Qbase + (size_t)qrow * ldq + 32 + l4 * 8);

    f32x4 o[4] = {};
    float m[4], lsum[4];
    #pragma unroll
    for (int r = 0; r < 4; ++r) { m[r] = -1e30f; lsum[r] = 0.f; }

    const int nt = (MODE == 1) ? (qb / 64 + 1) : (Sn / 64);
    const int nIt = (nt + 1) >> 1;

    if (g < nt) {
        stage_tile<64, 4>(Kbase + (size_t)(g * 64) * ldk, ldk, Ks[g][0], 0, w4, lane);
        stage_tile<64, 4>(Vbase, Sn, Vs[g][0], g * 64, w4, lane);
    }
    __syncthreads();

    for (int it = 0; it < nIt; ++it) {
        const int kt = 2 * it + g;
        const int cur = it & 1;
        if (kt + 2 < nt) {
            stage_tile<64, 4>(Kbase + (size_t)((kt + 2) * 64) * ldk, ldk, Ks[g][cur ^ 1], 0, w4, lane);
            stage_tile<64, 4>(Vbase, Sn, Vs[g][cur ^ 1], (kt + 2) * 64, w4, lane);
        }
        if (kt < nt) {
            f32x4 s[4] = {};
            #pragma unroll
            for (int ks = 0; ks < 2; ++ks) {
                const int st = ks * 4 + l4;
                #pragma unroll
                for (int j = 0; j < 4; ++j) {
                    s16x8 bv = ldrd(Ks[g][cur], j * 16 + l15, st);
                    s[j] = __builtin_amdgcn_mfma_f32_16x16x32_bf16(qv[ks], bv, s[j], 0, 0, 0);
                }
            }

            #pragma unroll
            for (int j = 0; j < 4; ++j) {
                const int col = kt * 64 + j * 16 + l15;
                #pragma unroll
                for (int r = 0; r < 4; ++r) {
                    float v = s[j][r] * 0.125f;
                    if (MODE == 0) { if (msk[col] != 0.f) v = -1e9f; }
                    else           { if (col > qb + w4 * 16 + l4 * 4 + r) v = -1e9f; }
                    s[j][r] = v;
                }
            }

            float mt[4];
            #pragma unroll
            for (int r = 0; r < 4; ++r)
                mt[r] = fmaxf(fmaxf(s[0][r], s[1][r]), fmaxf(s[2][r], s[3][r]));
            #pragma unroll
            for (int mk = 1; mk < 16; mk <<= 1)
                #pragma unroll
                for (int r = 0; r < 4; ++r)
                    mt[r] = fmaxf(mt[r], __shfl_xor(mt[r], mk));

            float al[4];
            #pragma unroll
            for (int r = 0; r < 4; ++r) {
                const float mn = fmaxf(m[r], mt[r]);
                al[r] = __expf(m[r] - mn);
                m[r] = mn;
            }

            float rs[4] = {0.f, 0.f, 0.f, 0.f};
            ushort_t* pw = Ps[w];
            #pragma unroll
            for (int j = 0; j < 4; ++j) {
                const int slot = j * 2 + (l15 >> 3), e = l15 & 7;
                #pragma unroll
                for (int r = 0; r < 4; ++r) {
                    const float pvv = __expf(s[j][r] - m[r]);
                    rs[r] += pvv;
                    const int row = l4 * 4 + r;
                    pw[row * 64 + ((slot ^ (row & 7)) << 3) + e] = f2bf(pvv);
                }
            }
            #pragma unroll
            for (int mk = 1; mk < 16; mk <<= 1)
                #pragma unroll
                for (int r = 0; r < 4; ++r)
                    rs[r] += __shfl_xor(rs[r], mk);
            #pragma unroll
            for (int r = 0; r < 4; ++r) lsum[r] = lsum[r] * al[r] + rs[r];

            #pragma unroll
            for (int jd = 0; jd < 4; ++jd)
                #pragma unroll
                for (int r = 0; r < 4; ++r)
                    o[jd][r] *= al[r];
            #pragma unroll
            for (int ks2 = 0; ks2 < 2; ++ks2) {
                const int st2 = ks2 * 4 + l4;
                s16x8 pa = ldrd(pw, l15, st2);
                #pragma unroll
                for (int jd = 0; jd < 4; ++jd) {
                    s16x8 bv2 = ldrd(Vs[g][cur], jd * 16 + l15, st2);
                    o[jd] = __builtin_amdgcn_mfma_f32_16x16x32_bf16(pa, bv2, o[jd], 0, 0, 0);
                }
            }
        }
        __syncthreads();
    }

    // ---- merge group 1 into group 0, then write ----
    if (g == 1) {
        float* mp = mrg[w4][lane];
        #pragma unroll
        for (int jd = 0; jd < 4; ++jd)
            #pragma unroll
            for (int r = 0; r < 4; ++r)
                mp[jd * 4 + r] = o[jd][r];
        #pragma unroll
        for (int r = 0; r < 4; ++r) { mp[16 + r] = m[r]; mp[20 + r] = lsum[r]; }
    }
    __syncthreads();
    if (g == 0) {
        const float* mp = mrg[w4][lane];
        float a0[4], a1[4], inv[4];
        #pragma unroll
        for (int r = 0; r < 4; ++r) {
            const float m1 = mp[16 + r];
            const float mm = fmaxf(m[r], m1);
            a0[r] = __expf(m[r] - mm);
            a1[r] = __expf(m1 - mm);
            inv[r] = 1.f / (lsum[r] * a0[r] + mp[20 + r] * a1[r]);
        }
        #pragma unroll
        for (int jd = 0; jd < 4; ++jd)
            #pragma unroll
            for (int r = 0; r < 4; ++r)
                Obase[(size_t)(w4 * 16 + l4 * 4 + r) * Dm + jd * 16 + l15] =
                    f2bf((o[jd][r] * a0[r] + mp[jd * 4 + r] * a1[r]) * inv[r]);
    }
}

// ---------------------------------------------------------------------------
// Merged weight transpose+cvt: 12 weight groups, one dispatch.
// dls = per-layer stride of dst.
// ---------------------------------------------------------------------------
struct WEnt { const float* src; ushort_t* dst; int R, C, tile0; long dls; };
struct WPack { WEnt e[12]; };

__global__ __launch_bounds__(256) void wcvt_all(WPack p)
{
    const int bid = blockIdx.x;
    int i = 0;
    #pragma unroll
    for (int k = 1; k < 12; ++k) if (bid >= p.e[k].tile0) i = k;
    const WEnt wd = p.e[i];
    const int rel = bid - wd.tile0;
    const int tC = wd.C >> 5, tR = wd.R >> 5;
    const int tpl = tC * tR;
    const int l = rel / tpl, t2 = rel - l * tpl;
    const int ty = t2 / tC, tx = t2 - ty * tC;

    const float* in  = wd.src + (size_t)l * wd.R * wd.C;
    ushort_t*    out = wd.dst + (size_t)l * wd.dls;

    __shared__ float tbuf[32][33];
    const int r0 = ty * 32, c0 = tx * 32;
    const int tid = threadIdx.x;
    const int r = tid >> 5, c = tid & 31;
    #pragma unroll
    for (int q = 0; q < 4; ++q)
        tbuf[r + q * 8][c] = in[(size_t)(r0 + r + q * 8) * wd.C + c0 + c];
    __syncthreads();
    const int c2 = tid >> 5, r2 = tid & 31;
    #pragma unroll
    for (int q = 0; q < 4; ++q)
        out[(size_t)(c0 + c2 + q * 8) * wd.R + r0 + r2] = f2bf(tbuf[r2][c2 + q * 8]);
}

// ---------------------------------------------------------------------------
// x = layernorm(s0 + s1 + xres)*g + b  (s0,s1 = split-K partials).
// Writes fp32 x (in-place ok: xres may alias x) and bf16 xbf.
// ---------------------------------------------------------------------------
__global__ __launch_bounds__(256) void ln_sum3(
    const float* __restrict__ s0, const float* __restrict__ s1,
    const float* __restrict__ xres, float* __restrict__ x,
    const float* __restrict__ gam, const float* __restrict__ bet,
    ushort_t* __restrict__ xbf)
{
    const long row = blockIdx.x;
    const int t = threadIdx.x;
    const long base = row * Dm;
    float v0 = s0[base + t]       + s1[base + t]       + xres[base + t];
    float v1 = s0[base + t + 256] + s1[base + t + 256] + xres[base + t + 256];

    float sum = v0 + v1, ssq = v0 * v0 + v1 * v1;
    __shared__ float red[8];
    for (int off = 32; off; off >>= 1) {
        sum += __shfl_down(sum, off);
        ssq += __shfl_down(ssq, off);
    }
    const int lane = t & 63, w = t >> 6;
    if (lane == 0) { red[w] = sum; red[4 + w] = ssq; }
    __syncthreads();
    sum = red[0] + red[1] + red[2] + red[3];
    ssq = red[4] + red[5] + red[6] + red[7];

    const float mean = sum * (1.f / Dm);
    const float var  = ssq * (1.f / Dm) - mean * mean;
    const float r = rsqrtf(var + 1e-5f);
    const float r0 = (v0 - mean) * r * gam[t] + bet[t];
    const float r1 = (v1 - mean) * r * gam[t + 256] + bet[t + 256];
    x[base + t] = r0; x[base + t + 256] = r1;
    xbf[base + t] = f2bf(r0);
    xbf[base + t + 256] = f2bf(r1);
}

// ---------------------------------------------------------------------------
// Embeddings for both streams in one dispatch: grid.y 0 -> src, 1 -> trg.
// ---------------------------------------------------------------------------
__global__ __launch_bounds__(256) void embed_pe(
    const int* __restrict__ tokA, const float* __restrict__ embA,
    float* __restrict__ outA, ushort_t* __restrict__ outbfA,
    const int* __restrict__ tokB, const float* __restrict__ embB,
    float* __restrict__ outB, ushort_t* __restrict__ outbfB)
{
    const int bs = blockIdx.x;
    const int s = bs % Sn;
    const int t = threadIdx.x;
    const int*      tok   = blockIdx.y ? tokB : tokA;
    const float*    emb   = blockIdx.y ? embB : embA;
    float*          out   = blockIdx.y ? outB : outA;
    ushort_t*       outbf = blockIdx.y ? outbfB : outbfA;
    const int token = tok[bs];
    #pragma unroll
    for (int r = 0; r < 2; ++r) {
        const int d = t + r * 256;
        const int i = d & ~1;
        const float ang = (float)s * powf(10000.0f, -(float)i / (float)Dm);
        const float pe = (d & 1) ? cosf(ang) : sinf(ang);
        const float v = emb[(size_t)token * Dm + d] * 22.627416997969522f + pe;
        out[(size_t)bs * Dm + d] = v;
        outbf[(size_t)bs * Dm + d] = f2bf(v);
    }
}

// ---------------------------------------------------------------------------
extern "C" void kernel_launch(void* const* d_in, const int* in_sizes, int n_in,
                              void* d_out, int out_size, void* d_ws, size_t ws_size,
                              hipStream_t stream)
{
    const int*   batch_src = (const int*)d_in[0];
    const int*   trg       = (const int*)d_in[1];
    const float* src_emb   = (const float*)d_in[2];
    const float* trg_emb   = (const float*)d_in[3];
    const float* fc_w      = (const float*)d_in[4];
    const float* fc_b      = (const float*)d_in[5];
    const float* enc_wqkv  = (const float*)d_in[6];
    const float* enc_wo    = (const float*)d_in[7];
    const float* enc_ln1s  = (const float*)d_in[8];
    const float* enc_ln1b  = (const float*)d_in[9];
    const float* enc_w1    = (const float*)d_in[10];
    const float* enc_b1    = (const float*)d_in[11];
    const float* enc_w2    = (const float*)d_in[12];
    const float* enc_b2    = (const float*)d_in[13];
    const float* enc_ln2s  = (const float*)d_in[14];
    const float* enc_ln2b  = (const float*)d_in[15];
    const float* dec_wqkv  = (const float*)d_in[16];
    const float* dec_wo    = (const float*)d_in[17];
    const float* dec_ln1s  = (const float*)d_in[18];
    const float* dec_ln1b  = (const float*)d_in[19];
    const float* dec_wq    = (const float*)d_in[20];
    const float* dec_wkv   = (const float*)d_in[21];
    const float* dec_woc   = (const float*)d_in[22];
    const float* dec_ln2s  = (const float*)d_in[23];
    const float* dec_ln2b  = (const float*)d_in[24];
    const float* dec_w1    = (const float*)d_in[25];
    const float* dec_b1    = (const float*)d_in[26];
    const float* dec_w2    = (const float*)d_in[27];
    const float* dec_b2    = (const float*)d_in[28];
    const float* dec_ln3s  = (const float*)d_in[29];
    const float* dec_ln3b  = (const float*)d_in[30];
    (void)in_sizes; (void)n_in; (void)out_size; (void)ws_size;

    char* p = (char*)d_ws;
    auto alloc = [&](size_t bytes) { char* r = p; p += (bytes + 255) & ~(size_t)255; return r; };
    float*    X     = (float*)alloc((size_t)Mrows * Dm * 4);
    float*    Y     = (float*)alloc((size_t)Mrows * Dm * 4);
    float*    O     = (float*)alloc((size_t)2 * Mrows * Dm * 4);   // split-K partials
    float*    O1    = O + (size_t)Mrows * Dm;
    ushort_t* Xbf   = (ushort_t*)alloc((size_t)Mrows * Dm * 2);
    ushort_t* Ybf   = (ushort_t*)alloc((size_t)Mrows * Dm * 2);
    ushort_t* QKVbf = (ushort_t*)alloc((size_t)Mrows * 3 * Dm * 2);
    ushort_t* QCbf  = (ushort_t*)alloc((size_t)Mrows * Dm * 2);
    ushort_t* AObf  = (ushort_t*)alloc((size_t)Mrows * Dm * 2);
    ushort_t* FHbf  = (ushort_t*)alloc((size_t)Mrows * DFFm * 2);
    ushort_t* VT    = (ushort_t*)alloc((size_t)16 * DHm * Sn * 2);
    ushort_t* KVC   = (ushort_t*)alloc((size_t)Ln * Mrows * 2 * Dm * 2);
    ushort_t* VTC   = (ushort_t*)alloc((size_t)Ln * 16 * DHm * Sn * 2);
    ushort_t* ewqkv_t = (ushort_t*)alloc((size_t)Ln * 3 * Dm * Dm * 2);
    ushort_t* ewo_t   = (ushort_t*)alloc((size_t)Ln * Dm * Dm * 2);
    ushort_t* ew1_t   = (ushort_t*)alloc((size_t)Ln * DFFm * Dm * 2);
    ushort_t* ew2_t   = (ushort_t*)alloc((size_t)Ln * Dm * DFFm * 2);
    ushort_t* dwqkv_t = (ushort_t*)alloc((size_t)Ln * 3 * Dm * Dm * 2);
    ushort_t* dwq_t   = (ushort_t*)alloc((size_t)Ln * Dm * Dm * 2);
    ushort_t* dwo_t   = (ushort_t*)alloc((size_t)Ln * Dm * Dm * 2);
    ushort_t* dwkv_t  = (ushort_t*)alloc((size_t)Ln * 2 * Dm * Dm * 2);
    ushort_t* dwoc_t  = (ushort_t*)alloc((size_t)Ln * Dm * Dm * 2);
    ushort_t* dw1_t   = (ushort_t*)alloc((size_t)Ln * DFFm * Dm * 2);
    ushort_t* dw2_t   = (ushort_t*)alloc((size_t)Ln * Dm * DFFm * 2);
    ushort_t* fcw_t   = (ushort_t*)alloc((size_t)Vm * Dm * 2);

    // ---------------- merged weight transpose+cvt (one dispatch) ----------
    {
        WPack pk;
        auto set = [&](int i, const float* s, ushort_t* d, int R, int C, int nl,
                       long dls, int& acc) {
            pk.e[i] = { s, d, R, C, acc, dls };
            acc += (R >> 5) * (C >> 5) * nl;
        };
        int acc = 0;
        set(0,  enc_wqkv, ewqkv_t, Dm,   3 * Dm, Ln, (long)3 * Dm * Dm, acc);
        set(1,  enc_wo,   ewo_t,   Dm,   Dm,     Ln, (long)Dm * Dm,     acc);
        set(2,  enc_w1,   ew1_t,   Dm,   DFFm,   Ln, (long)Dm * DFFm,   acc);
        set(3,  enc_w2,   ew2_t,   DFFm, Dm,     Ln, (long)Dm * DFFm,   acc);
        set(4,  dec_wqkv, dwqkv_t, Dm,   3 * Dm, Ln, (long)3 * Dm * Dm, acc);
        set(5,  dec_wq,   dwq_t,   Dm,   Dm,     Ln, (long)Dm * Dm,     acc);
        set(6,  dec_wo,   dwo_t,   Dm,   Dm,     Ln, (long)Dm * Dm,     acc);
        set(7,  dec_wkv,  dwkv_t,  Dm,   2 * Dm, Ln, (long)2 * Dm * Dm, acc);
        set(8,  dec_woc,  dwoc_t,  Dm,   Dm,     Ln, (long)Dm * Dm,     acc);
        set(9,  dec_w1,   dw1_t,   Dm,   DFFm,   Ln, (long)Dm * DFFm,   acc);
        set(10, dec_w2,   dw2_t,   DFFm, Dm,     Ln, (long)Dm * DFFm,   acc);
        set(11, fc_w,     fcw_t,   Dm,   Vm,     1,  (long)Dm * Vm,     acc);
        wcvt_all<<<acc, 256, 0, stream>>>(pk);
    }

    embed_pe<<<dim3(Mrows, 2), 256, 0, stream>>>(
        batch_src, src_emb, X, Xbf, trg, trg_emb, Y, Ybf);

    const long VTs  = (long)16 * DHm * Sn;   // per-layer VT stride (elements)
    const long Osb  = (long)Mrows * Dm;      // split-K partial stride

    // --------------------------------- encoder ----------------------------
    for (int l = 0; l < Ln; ++l) {
        gemm_bf<64,128,4,true,false,false,true,false><<<dim3(12, 32, 1), 256, 0, stream>>>(
            Xbf, ewqkv_t + (size_t)l * 3 * Dm * Dm, QKVbf, nullptr,
            Dm, Dm, Dm, 3 * Dm, 0,0,0,0,0,0, 1, VT, 2 * Dm, 0);
        flash_attn<0><<<dim3(16, 16), 512, 0, stream>>>(
            QKVbf, QKVbf + Dm, VT, AObf, batch_src, 3 * Dm, 3 * Dm);
        gemm_bf<64,64,8,false,false,false,false,false><<<dim3(8, 32, 2), 512, 0, stream>>>(
            AObf, ewo_t + (size_t)l * Dm * Dm, O, nullptr,
            256, Dm, Dm, Dm, 256, 0, 256, 0, Osb, 0, 1, nullptr, 0, 0);
        ln_sum3<<<Mrows, 256, 0, stream>>>(O, O1, X, X,
            enc_ln1s + l * Dm, enc_ln1b + l * Dm, Xbf);
        gemm_bf<64,128,4,true,true,true,false,false><<<dim3(16, 32, 1), 256, 0, stream>>>(
            Xbf, ew1_t + (size_t)l * DFFm * Dm, FHbf, enc_b1 + l * DFFm,
            Dm, Dm, Dm, DFFm, 0,0,0,0,0,0, 1, nullptr, 0, 0);
        gemm_bf<64,64,8,false,true,false,false,false><<<dim3(8, 32, 2), 512, 0, stream>>>(
            FHbf, ew2_t + (size_t)l * Dm * DFFm, O, enc_b2 + l * Dm,
            1024, DFFm, DFFm, Dm, 1024, 0, 1024, 0, Osb, 0, 1, nullptr, 0, 0);
        ln_sum3<<<Mrows, 256, 0, stream>>>(O, O1, X, X,
            enc_ln2s + l * Dm, enc_ln2b + l * Dm, Xbf);
    }

    // all 6 decoder cross-attn KV projections, one batched dispatch (z = layer)
    gemm_bf<64,128,4,true,false,false,true,false><<<dim3(8, 32, Ln), 256, 0, stream>>>(
        Xbf, dwkv_t, KVC, nullptr,
        Dm, Dm, Dm, 2 * Dm,
        0, 0, (long)2 * Dm * Dm, 0, (long)Mrows * 2 * Dm, 0, 1,
        VTC, Dm, VTs);

    // --------------------------------- decoder ----------------------------
    for (int l = 0; l < Ln; ++l) {
        // self-attention (causal)
        gemm_bf<64,128,4,true,false,false,true,false><<<dim3(12, 32, 1), 256, 0, stream>>>(
            Ybf, dwqkv_t + (size_t)l * 3 * Dm * Dm, QKVbf, nullptr,
            Dm, Dm, Dm, 3 * Dm, 0,0,0,0,0,0, 1, VT, 2 * Dm, 0);
        flash_attn<1><<<dim3(16, 16), 512, 0, stream>>>(
            QKVbf, QKVbf + Dm, VT, AObf, nullptr, 3 * Dm, 3 * Dm);
        gemm_bf<64,64,8,false,false,false,false,false><<<dim3(8, 32, 2), 512, 0, stream>>>(
            AObf, dwo_t + (size_t)l * Dm * Dm, O, nullptr,
            256, Dm, Dm, Dm, 256, 0, 256, 0, Osb, 0, 1, nullptr, 0, 0);
        ln_sum3<<<Mrows, 256, 0, stream>>>(O, O1, Y, Y,
            dec_ln1s + l * Dm, dec_ln1b + l * Dm, Ybf);

        // cross-attention (pad mask): qc = post-ln1 y @ wq  (reference-faithful)
        gemm_bf<64,64,8,true,false,false,false,false><<<dim3(8, 32, 1), 512, 0, stream>>>(
            Ybf, dwq_t + (size_t)l * Dm * Dm, QCbf, nullptr,
            Dm, Dm, Dm, Dm, 0,0,0,0,0,0, 1, nullptr, 0, 0);
        flash_attn<0><<<dim3(16, 16), 512, 0, stream>>>(
            QCbf, KVC + (size_t)l * Mrows * 2 * Dm,
            VTC + (size_t)l * VTs, AObf, batch_src, Dm, 2 * Dm);
        gemm_bf<64,64,8,false,false,false,false,false><<<dim3(8, 32, 2), 512, 0, stream>>>(
            AObf, dwoc_t + (size_t)l * Dm * Dm, O, nullptr,
            256, Dm, Dm, Dm, 256, 0, 256, 0, Osb, 0, 1, nullptr, 0, 0);
        ln_sum3<<<Mrows, 256, 0, stream>>>(O, O1, Y, Y,
            dec_ln2s + l * Dm, dec_ln2b + l * Dm, Ybf);

        // feed-forward
        gemm_bf<64,128,4,true,true,true,false,false><<<dim3(16, 32, 1), 256, 0, stream>>>(
            Ybf, dw1_t + (size_t)l * DFFm * Dm, FHbf, dec_b1 + l * DFFm,
            Dm, Dm, Dm, DFFm, 0,0,0,0,0,0, 1, nullptr, 0, 0);
        gemm_bf<64,64,8,false,true,false,false,false><<<dim3(8, 32, 2), 512, 0, stream>>>(
            FHbf, dw2_t + (size_t)l * Dm * DFFm, O, dec_b2 + l * Dm,
            1024, DFFm, DFFm, Dm, 1024, 0, 1024, 0, Osb, 0, 1, nullptr, 0, 0);
        ln_sum3<<<Mrows, 256, 0, stream>>>(O, O1, Y, Y,
            dec_ln3s + l * Dm, dec_ln3b + l * Dm, Ybf);
    }

    // final projection to vocab (XCD-swizzled, NW=8: 16 waves/CU for TLP)
    gemm_bf<128,128,8,false,true,false,false,true><<<dim3(Vm / 128, 16, 1), 512, 0, stream>>>(
        Ybf, fcw_t, (float*)d_out, fc_b,
        Dm, Dm, Dm, Vm, 0,0,0,0,0,0, 1, nullptr, 0, 0);
}

// Round 16
// 1487.147 us; speedup vs baseline: 1.0052x; 1.0052x over previous
//
#include <hip/hip_runtime.h>
#include <cmath>

#define Dm   512
#define Hn   8
#define Ln   6
#define DFFm 2048
#define Vm   32000
#define Bn   2
#define Sn   1024
#define DHm  64
#define Mrows (Bn*Sn)   // 2048

typedef unsigned short ushort_t;
typedef __attribute__((ext_vector_type(8))) short          s16x8;
typedef __attribute__((ext_vector_type(8))) unsigned short u16x8;
typedef __attribute__((ext_vector_type(4))) float          f32x4;

__device__ __forceinline__ ushort_t f2bf(float x) {
    union { float f; unsigned u; } un; un.f = x;
    unsigned r = un.u + 0x7fffu + ((un.u >> 16) & 1u);
    return (ushort_t)(r >> 16);
}

// ---------------------------------------------------------------------------
// Stage TR rows x 64 k of bf16 from global into a swizzled LDS tile,
// cooperatively across NW waves (T2 swizzle via pre-swizzled source;
// global_load_lds writes linearly).
// ---------------------------------------------------------------------------
template<int TR, int NW>
__device__ __forceinline__ void stage_tile(const ushort_t* __restrict__ src, int ld,
                                           ushort_t* lds, int k0, int w, int lane)
{
    constexpr int CH = TR / (8 * NW);           // row-chunks per wave
    #pragma unroll
    for (int c = 0; c < CH; ++c) {
        const int rb = (w * CH + c) * 8;        // wave-uniform row base
        const int r  = rb + (lane >> 3);
        const ushort_t* gp = src + (size_t)r * ld + k0
                           + (((lane & 7) ^ ((lane >> 3) & 7)) << 3);
        __builtin_amdgcn_global_load_lds(
            (const __attribute__((address_space(1))) void*)gp,
            (__attribute__((address_space(3))) void*)(lds + rb * 64),
            16, 0, 0);
    }
}

// read 8 bf16: LDS tile row r, logical 16B-slot st (0..7)
__device__ __forceinline__ s16x8 ldrd(const ushort_t* lds, int r, int st)
{
    return *(const s16x8*)&lds[r * 64 + ((st ^ (r & 7)) << 3)];
}

// ---------------------------------------------------------------------------
// bf16 MFMA GEMM: C[M,N] = A[M,K] @ Bt[N,K]^T  (+bias) (+relu)
// Double-buffered LDS, 1-deep prefetch, one barrier per K-step.
// NW = waves/block (TLP lever): 4 -> 2x2 wave grid; 8 -> 2x4 (512 threads).
//   NW=8 pays only when blocks/CU is the binding constraint (64x64 GEMMs);
//   at 128^2 it dilutes per-wave MFMA density (measured regression, r15).
// Split-K usage: grid.z=2 with nh=1, A_sb=B_sb=K_half, C_sb = partial stride,
//   K=K_half. Bias applied only by blockIdx.z==0.
// VTOUT: cols in [voff, voff+512) are written transposed to
//   (VTp + z*VT_sz)[zz][d][s]; other cols fall through to row-major C.
// SWZ (fc only): XCD-aware bijective remap (weight panels HBM-fetched once).
// ---------------------------------------------------------------------------
template<int TM, int TN, int NW, bool OBF, bool BIAS, bool RELU, bool VTOUT, bool SWZ>
__global__ __launch_bounds__(NW * 64) void gemm_bf(
    const ushort_t* __restrict__ A, const ushort_t* __restrict__ Bt,
    void* __restrict__ Cv, const float* __restrict__ bias,
    int K, int lda, int ldb, int ldc,
    long A_sb, long A_sh, long B_sb, long B_sh, long C_sb, long C_sh, int nh,
    ushort_t* __restrict__ VTp, int voff, long VT_sz)
{
    constexpr int WC = NW / 2;                  // wave-grid cols (2 or 4)
    constexpr int FI = TM / 32;                 // frags per wave, M dir
    constexpr int FJ = TN / (16 * WC);          // frags per wave, N dir
    __shared__ __align__(16) ushort_t As[2][TM * 64];
    __shared__ __align__(16) ushort_t Bs[2][TN * 64];

    const int z = blockIdx.z, b = z / nh, h = z - b * nh;
    A  += (size_t)b * A_sb + (size_t)h * A_sh;
    Bt += (size_t)b * B_sb + (size_t)h * B_sh;
    ushort_t* VTl = VTp + (size_t)z * VT_sz;

    int bx = blockIdx.x, by = blockIdx.y;
    if constexpr (SWZ) {
        const int ncol = gridDim.x, nrow = gridDim.y;
        const int total = ncol * nrow;
        const int flat = bx + by * ncol;          // dispatch order (x fastest)
        const int per = total >> 3;
        const int g = (flat & 7) * per + (flat >> 3);
        bx = g / nrow;
        by = g - bx * nrow;
    }

    const int tid  = threadIdx.x;
    const int w    = tid >> 6, lane = tid & 63;
    const int m0   = by * TM, n0 = bx * TN;
    const int rw   = (w / WC) * (TM / 2);       // wave sub-tile row base
    const int cn   = (w % WC) * (TN / WC);      // wave sub-tile col base
    const int l15  = lane & 15, l4 = lane >> 4;

    const ushort_t* Ab = A + (size_t)m0 * lda;
    const ushort_t* Bb = Bt + (size_t)n0 * ldb;

    f32x4 acc[FI][FJ] = {};

    stage_tile<TM, NW>(Ab, lda, As[0], 0, w, lane);
    stage_tile<TN, NW>(Bb, ldb, Bs[0], 0, w, lane);
    __syncthreads();

    const int nk = K >> 6;
    for (int t = 0; t < nk; ++t) {
        const int cur = t & 1;
        if (t + 1 < nk) {
            stage_tile<TM, NW>(Ab, lda, As[cur ^ 1], (t + 1) << 6, w, lane);
            stage_tile<TN, NW>(Bb, ldb, Bs[cur ^ 1], (t + 1) << 6, w, lane);
        }
        #pragma unroll
        for (int ks = 0; ks < 2; ++ks) {
            const int st = ks * 4 + l4;
            s16x8 av[FI], bv[FJ];
            #pragma unroll
            for (int i = 0; i < FI; ++i) av[i] = ldrd(As[cur], rw + i * 16 + l15, st);
            #pragma unroll
            for (int j = 0; j < FJ; ++j) bv[j] = ldrd(Bs[cur], cn + j * 16 + l15, st);
            #pragma unroll
            for (int i = 0; i < FI; ++i)
                #pragma unroll
                for (int j = 0; j < FJ; ++j)
                    acc[i][j] = __builtin_amdgcn_mfma_f32_16x16x32_bf16(
                                    av[i], bv[j], acc[i][j], 0, 0, 0);
        }
        __syncthreads();
    }

    // epilogue: D[col=lane&15, row=(lane>>4)*4 + r]  (m89-verified layout)
    const int colb = n0 + cn + l15;
    const int rowb = m0 + rw + (l4 << 2);
    const bool doBias = BIAS && (blockIdx.z == 0);
    float bvv[FJ];
    #pragma unroll
    for (int j = 0; j < FJ; ++j) bvv[j] = doBias ? bias[colb + j * 16] : 0.f;

    if constexpr (OBF) {
        ushort_t* C = (ushort_t*)Cv + (size_t)b * C_sb + (size_t)h * C_sh;
        #pragma unroll
        for (int i = 0; i < FI; ++i)
            #pragma unroll
            for (int r = 0; r < 4; ++r) {
                const int row = rowb + i * 16 + r;
                #pragma unroll
                for (int j = 0; j < FJ; ++j) {
                    float v = acc[i][j][r] + bvv[j];
                    if (RELU) v = fmaxf(v, 0.f);
                    const int col = colb + j * 16;
                    if (VTOUT && col >= voff && col < voff + 512) {
                        const int hc = (col - voff) >> 6, d = (col - voff) & 63;
                        const int zz = (row >> 10) * 8 + hc;
                        VTl[(size_t)zz * (64 * Sn) + (size_t)d * Sn + (row & (Sn - 1))] = f2bf(v);
                    } else {
                        C[(size_t)row * ldc + col] = f2bf(v);
                    }
                }
            }
    } else {
        float* C = (float*)Cv + (size_t)b * C_sb + (size_t)h * C_sh;
        #pragma unroll
        for (int i = 0; i < FI; ++i)
            #pragma unroll
            for (int r = 0; r < 4; ++r) {
                const size_t row = rowb + i * 16 + r;
                #pragma unroll
                for (int j = 0; j < FJ; ++j) {
                    float v = acc[i][j][r] + bvv[j];
                    if (RELU) v = fmaxf(v, 0.f);
                    C[row * ldc + colb + j * 16] = v;
                }
            }
    }
}

// ---------------------------------------------------------------------------
// Flash-fused attention, KV-split across 2 wave groups (8 waves, 512 thr).
// MODE 0: pad mask; MODE 1: causal. (See round-10 notes.)
// ---------------------------------------------------------------------------
template<int MODE>
__global__ __launch_bounds__(512) void flash_attn(
    const ushort_t* __restrict__ Qp, const ushort_t* __restrict__ Kp,
    const ushort_t* __restrict__ VTp, ushort_t* __restrict__ AO,
    const int* __restrict__ tok, int ldq, int ldk)
{
    __shared__ __align__(16) ushort_t Ks[2][2][64 * 64];   // [group][buf]
    __shared__ __align__(16) ushort_t Vs[2][2][64 * 64];
    __shared__ __align__(16) ushort_t Ps[8][16 * 64];
    __shared__ float msk[Sn];
    __shared__ float mrg[4][64][25];   // group-1 partials: 16 o + 4 m + 4 l

    const int z = blockIdx.y, b = z >> 3, h = z & 7;
    const int qb = blockIdx.x * 64;
    const int tid = threadIdx.x, w = tid >> 6, lane = tid & 63;
    const int g = w >> 2, w4 = w & 3;
    const int l15 = lane & 15, l4 = lane >> 4;

    const ushort_t* Qbase = Qp + (size_t)b * Sn * ldq + h * 64;
    const ushort_t* Kbase = Kp + (size_t)b * Sn * ldk + h * 64;
    const ushort_t* Vbase = VTp + (size_t)z * 64 * Sn;
    ushort_t* Obase = AO + ((size_t)(b * Sn + qb)) * Dm + h * 64;

    if (MODE == 0) {
        const int* tb = tok + (size_t)b * Sn;
        for (int i = tid; i < Sn; i += 512) msk[i] = (tb[i] == 0) ? 1.f : 0.f;
    }

    const int qrow = qb + w4 * 16 + l15;
    s16x8 qv[2];
    qv[0] = *(const s16x8*)(Qbase + (size_t)qrow * ldq + l4 * 8);
    qv[1] = *(const s16x8*)(Qbase + (size_t)qrow * ldq + 32 + l4 * 8);

    f32x4 o[4] = {};
    float m[4], lsum[4];
    #pragma unroll
    for (int r = 0; r < 4; ++r) { m[r] = -1e30f; lsum[r] = 0.f; }

    const int nt = (MODE == 1) ? (qb / 64 + 1) : (Sn / 64);
    const int nIt = (nt + 1) >> 1;

    if (g < nt) {
        stage_tile<64, 4>(Kbase + (size_t)(g * 64) * ldk, ldk, Ks[g][0], 0, w4, lane);
        stage_tile<64, 4>(Vbase, Sn, Vs[g][0], g * 64, w4, lane);
    }
    __syncthreads();

    for (int it = 0; it < nIt; ++it) {
        const int kt = 2 * it + g;
        const int cur = it & 1;
        if (kt + 2 < nt) {
            stage_tile<64, 4>(Kbase + (size_t)((kt + 2) * 64) * ldk, ldk, Ks[g][cur ^ 1], 0, w4, lane);
            stage_tile<64, 4>(Vbase, Sn, Vs[g][cur ^ 1], (kt + 2) * 64, w4, lane);
        }
        if (kt < nt) {
            f32x4 s[4] = {};
            #pragma unroll
            for (int ks = 0; ks < 2; ++ks) {
                const int st = ks * 4 + l4;
                #pragma unroll
                for (int j = 0; j < 4; ++j) {
                    s16x8 bv = ldrd(Ks[g][cur], j * 16 + l15, st);
                    s[j] = __builtin_amdgcn_mfma_f32_16x16x32_bf16(qv[ks], bv, s[j], 0, 0, 0);
                }
            }

            #pragma unroll
            for (int j = 0; j < 4; ++j) {
                const int col = kt * 64 + j * 16 + l15;
                #pragma unroll
                for (int r = 0; r < 4; ++r) {
                    float v = s[j][r] * 0.125f;
                    if (MODE == 0) { if (msk[col] != 0.f) v = -1e9f; }
                    else           { if (col > qb + w4 * 16 + l4 * 4 + r) v = -1e9f; }
                    s[j][r] = v;
                }
            }

            float mt[4];
            #pragma unroll
            for (int r = 0; r < 4; ++r)
                mt[r] = fmaxf(fmaxf(s[0][r], s[1][r]), fmaxf(s[2][r], s[3][r]));
            #pragma unroll
            for (int mk = 1; mk < 16; mk <<= 1)
                #pragma unroll
                for (int r = 0; r < 4; ++r)
                    mt[r] = fmaxf(mt[r], __shfl_xor(mt[r], mk));

            float al[4];
            #pragma unroll
            for (int r = 0; r < 4; ++r) {
                const float mn = fmaxf(m[r], mt[r]);
                al[r] = __expf(m[r] - mn);
                m[r] = mn;
            }

            float rs[4] = {0.f, 0.f, 0.f, 0.f};
            ushort_t* pw = Ps[w];
            #pragma unroll
            for (int j = 0; j < 4; ++j) {
                const int slot = j * 2 + (l15 >> 3), e = l15 & 7;
                #pragma unroll
                for (int r = 0; r < 4; ++r) {
                    const float pvv = __expf(s[j][r] - m[r]);
                    rs[r] += pvv;
                    const int row = l4 * 4 + r;
                    pw[row * 64 + ((slot ^ (row & 7)) << 3) + e] = f2bf(pvv);
                }
            }
            #pragma unroll
            for (int mk = 1; mk < 16; mk <<= 1)
                #pragma unroll
                for (int r = 0; r < 4; ++r)
                    rs[r] += __shfl_xor(rs[r], mk);
            #pragma unroll
            for (int r = 0; r < 4; ++r) lsum[r] = lsum[r] * al[r] + rs[r];

            #pragma unroll
            for (int jd = 0; jd < 4; ++jd)
                #pragma unroll
                for (int r = 0; r < 4; ++r)
                    o[jd][r] *= al[r];
            #pragma unroll
            for (int ks2 = 0; ks2 < 2; ++ks2) {
                const int st2 = ks2 * 4 + l4;
                s16x8 pa = ldrd(pw, l15, st2);
                #pragma unroll
                for (int jd = 0; jd < 4; ++jd) {
                    s16x8 bv2 = ldrd(Vs[g][cur], jd * 16 + l15, st2);
                    o[jd] = __builtin_amdgcn_mfma_f32_16x16x32_bf16(pa, bv2, o[jd], 0, 0, 0);
                }
            }
        }
        __syncthreads();
    }

    // ---- merge group 1 into group 0, then write ----
    if (g == 1) {
        float* mp = mrg[w4][lane];
        #pragma unroll
        for (int jd = 0; jd < 4; ++jd)
            #pragma unroll
            for (int r = 0; r < 4; ++r)
                mp[jd * 4 + r] = o[jd][r];
        #pragma unroll
        for (int r = 0; r < 4; ++r) { mp[16 + r] = m[r]; mp[20 + r] = lsum[r]; }
    }
    __syncthreads();
    if (g == 0) {
        const float* mp = mrg[w4][lane];
        float a0[4], a1[4], inv[4];
        #pragma unroll
        for (int r = 0; r < 4; ++r) {
            const float m1 = mp[16 + r];
            const float mm = fmaxf(m[r], m1);
            a0[r] = __expf(m[r] - mm);
            a1[r] = __expf(m1 - mm);
            inv[r] = 1.f / (lsum[r] * a0[r] + mp[20 + r] * a1[r]);
        }
        #pragma unroll
        for (int jd = 0; jd < 4; ++jd)
            #pragma unroll
            for (int r = 0; r < 4; ++r)
                Obase[(size_t)(w4 * 16 + l4 * 4 + r) * Dm + jd * 16 + l15] =
                    f2bf((o[jd][r] * a0[r] + mp[jd * 4 + r] * a1[r]) * inv[r]);
    }
}

// ---------------------------------------------------------------------------
// Merged weight transpose+cvt: 12 weight groups, one dispatch.
// dls = per-layer stride of dst.
// ---------------------------------------------------------------------------
struct WEnt { const float* src; ushort_t* dst; int R, C, tile0; long dls; };
struct WPack { WEnt e[12]; };

__global__ __launch_bounds__(256) void wcvt_all(WPack p)
{
    const int bid = blockIdx.x;
    int i = 0;
    #pragma unroll
    for (int k = 1; k < 12; ++k) if (bid >= p.e[k].tile0) i = k;
    const WEnt wd = p.e[i];
    const int rel = bid - wd.tile0;
    const int tC = wd.C >> 5, tR = wd.R >> 5;
    const int tpl = tC * tR;
    const int l = rel / tpl, t2 = rel - l * tpl;
    const int ty = t2 / tC, tx = t2 - ty * tC;

    const float* in  = wd.src + (size_t)l * wd.R * wd.C;
    ushort_t*    out = wd.dst + (size_t)l * wd.dls;

    __shared__ float tbuf[32][33];
    const int r0 = ty * 32, c0 = tx * 32;
    const int tid = threadIdx.x;
    const int r = tid >> 5, c = tid & 31;
    #pragma unroll
    for (int q = 0; q < 4; ++q)
        tbuf[r + q * 8][c] = in[(size_t)(r0 + r + q * 8) * wd.C + c0 + c];
    __syncthreads();
    const int c2 = tid >> 5, r2 = tid & 31;
    #pragma unroll
    for (int q = 0; q < 4; ++q)
        out[(size_t)(c0 + c2 + q * 8) * wd.R + r0 + r2] = f2bf(tbuf[r2][c2 + q * 8]);
}

// ---------------------------------------------------------------------------
// x = layernorm(s0 + s1 + xres)*g + b  (s0,s1 = split-K partials).
// Writes fp32 x (in-place ok: xres may alias x) and bf16 xbf.
// ---------------------------------------------------------------------------
__global__ __launch_bounds__(256) void ln_sum3(
    const float* __restrict__ s0, const float* __restrict__ s1,
    const float* __restrict__ xres, float* __restrict__ x,
    const float* __restrict__ gam, const float* __restrict__ bet,
    ushort_t* __restrict__ xbf)
{
    const long row = blockIdx.x;
    const int t = threadIdx.x;
    const long base = row * Dm;
    float v0 = s0[base + t]       + s1[base + t]       + xres[base + t];
    float v1 = s0[base + t + 256] + s1[base + t + 256] + xres[base + t + 256];

    float sum = v0 + v1, ssq = v0 * v0 + v1 * v1;
    __shared__ float red[8];
    for (int off = 32; off; off >>= 1) {
        sum += __shfl_down(sum, off);
        ssq += __shfl_down(ssq, off);
    }
    const int lane = t & 63, w = t >> 6;
    if (lane == 0) { red[w] = sum; red[4 + w] = ssq; }
    __syncthreads();
    sum = red[0] + red[1] + red[2] + red[3];
    ssq = red[4] + red[5] + red[6] + red[7];

    const float mean = sum * (1.f / Dm);
    const float var  = ssq * (1.f / Dm) - mean * mean;
    const float r = rsqrtf(var + 1e-5f);
    const float r0 = (v0 - mean) * r * gam[t] + bet[t];
    const float r1 = (v1 - mean) * r * gam[t + 256] + bet[t + 256];
    x[base + t] = r0; x[base + t + 256] = r1;
    xbf[base + t] = f2bf(r0);
    xbf[base + t + 256] = f2bf(r1);
}

// ---------------------------------------------------------------------------
// Embeddings for both streams in one dispatch: grid.y 0 -> src, 1 -> trg.
// ---------------------------------------------------------------------------
__global__ __launch_bounds__(256) void embed_pe(
    const int* __restrict__ tokA, const float* __restrict__ embA,
    float* __restrict__ outA, ushort_t* __restrict__ outbfA,
    const int* __restrict__ tokB, const float* __restrict__ embB,
    float* __restrict__ outB, ushort_t* __restrict__ outbfB)
{
    const int bs = blockIdx.x;
    const int s = bs % Sn;
    const int t = threadIdx.x;
    const int*      tok   = blockIdx.y ? tokB : tokA;
    const float*    emb   = blockIdx.y ? embB : embA;
    float*          out   = blockIdx.y ? outB : outA;
    ushort_t*       outbf = blockIdx.y ? outbfB : outbfA;
    const int token = tok[bs];
    #pragma unroll
    for (int r = 0; r < 2; ++r) {
        const int d = t + r * 256;
        const int i = d & ~1;
        const float ang = (float)s * powf(10000.0f, -(float)i / (float)Dm);
        const float pe = (d & 1) ? cosf(ang) : sinf(ang);
        const float v = emb[(size_t)token * Dm + d] * 22.627416997969522f + pe;
        out[(size_t)bs * Dm + d] = v;
        outbf[(size_t)bs * Dm + d] = f2bf(v);
    }
}

// ---------------------------------------------------------------------------
extern "C" void kernel_launch(void* const* d_in, const int* in_sizes, int n_in,
                              void* d_out, int out_size, void* d_ws, size_t ws_size,
                              hipStream_t stream)
{
    const int*   batch_src = (const int*)d_in[0];
    const int*   trg       = (const int*)d_in[1];
    const float* src_emb   = (const float*)d_in[2];
    const float* trg_emb   = (const float*)d_in[3];
    const float* fc_w      = (const float*)d_in[4];
    const float* fc_b      = (const float*)d_in[5];
    const float* enc_wqkv  = (const float*)d_in[6];
    const float* enc_wo    = (const float*)d_in[7];
    const float* enc_ln1s  = (const float*)d_in[8];
    const float* enc_ln1b  = (const float*)d_in[9];
    const float* enc_w1    = (const float*)d_in[10];
    const float* enc_b1    = (const float*)d_in[11];
    const float* enc_w2    = (const float*)d_in[12];
    const float* enc_b2    = (const float*)d_in[13];
    const float* enc_ln2s  = (const float*)d_in[14];
    const float* enc_ln2b  = (const float*)d_in[15];
    const float* dec_wqkv  = (const float*)d_in[16];
    const float* dec_wo    = (const float*)d_in[17];
    const float* dec_ln1s  = (const float*)d_in[18];
    const float* dec_ln1b  = (const float*)d_in[19];
    const float* dec_wq    = (const float*)d_in[20];
    const float* dec_wkv   = (const float*)d_in[21];
    const float* dec_woc   = (const float*)d_in[22];
    const float* dec_ln2s  = (const float*)d_in[23];
    const float* dec_ln2b  = (const float*)d_in[24];
    const float* dec_w1    = (const float*)d_in[25];
    const float* dec_b1    = (const float*)d_in[26];
    const float* dec_w2    = (const float*)d_in[27];
    const float* dec_b2    = (const float*)d_in[28];
    const float* dec_ln3s  = (const float*)d_in[29];
    const float* dec_ln3b  = (const float*)d_in[30];
    (void)in_sizes; (void)n_in; (void)out_size; (void)ws_size;

    char* p = (char*)d_ws;
    auto alloc = [&](size_t bytes) { char* r = p; p += (bytes + 255) & ~(size_t)255; return r; };
    float*    X     = (float*)alloc((size_t)Mrows * Dm * 4);
    float*    Y     = (float*)alloc((size_t)Mrows * Dm * 4);
    float*    O     = (float*)alloc((size_t)2 * Mrows * Dm * 4);   // split-K partials
    float*    O1    = O + (size_t)Mrows * Dm;
    ushort_t* Xbf   = (ushort_t*)alloc((size_t)Mrows * Dm * 2);
    ushort_t* Ybf   = (ushort_t*)alloc((size_t)Mrows * Dm * 2);
    ushort_t* QKVbf = (ushort_t*)alloc((size_t)Mrows * 3 * Dm * 2);
    ushort_t* QCbf  = (ushort_t*)alloc((size_t)Mrows * Dm * 2);
    ushort_t* AObf  = (ushort_t*)alloc((size_t)Mrows * Dm * 2);
    ushort_t* FHbf  = (ushort_t*)alloc((size_t)Mrows * DFFm * 2);
    ushort_t* VT    = (ushort_t*)alloc((size_t)16 * DHm * Sn * 2);
    ushort_t* KVC   = (ushort_t*)alloc((size_t)Ln * Mrows * 2 * Dm * 2);
    ushort_t* VTC   = (ushort_t*)alloc((size_t)Ln * 16 * DHm * Sn * 2);
    ushort_t* ewqkv_t = (ushort_t*)alloc((size_t)Ln * 3 * Dm * Dm * 2);
    ushort_t* ewo_t   = (ushort_t*)alloc((size_t)Ln * Dm * Dm * 2);
    ushort_t* ew1_t   = (ushort_t*)alloc((size_t)Ln * DFFm * Dm * 2);
    ushort_t* ew2_t   = (ushort_t*)alloc((size_t)Ln * Dm * DFFm * 2);
    ushort_t* dwqkv_t = (ushort_t*)alloc((size_t)Ln * 3 * Dm * Dm * 2);
    ushort_t* dwq_t   = (ushort_t*)alloc((size_t)Ln * Dm * Dm * 2);
    ushort_t* dwo_t   = (ushort_t*)alloc((size_t)Ln * Dm * Dm * 2);
    ushort_t* dwkv_t  = (ushort_t*)alloc((size_t)Ln * 2 * Dm * Dm * 2);
    ushort_t* dwoc_t  = (ushort_t*)alloc((size_t)Ln * Dm * Dm * 2);
    ushort_t* dw1_t   = (ushort_t*)alloc((size_t)Ln * DFFm * Dm * 2);
    ushort_t* dw2_t   = (ushort_t*)alloc((size_t)Ln * Dm * DFFm * 2);
    ushort_t* fcw_t   = (ushort_t*)alloc((size_t)Vm * Dm * 2);

    // ---------------- merged weight transpose+cvt (one dispatch) ----------
    {
        WPack pk;
        auto set = [&](int i, const float* s, ushort_t* d, int R, int C, int nl,
                       long dls, int& acc) {
            pk.e[i] = { s, d, R, C, acc, dls };
            acc += (R >> 5) * (C >> 5) * nl;
        };
        int acc = 0;
        set(0,  enc_wqkv, ewqkv_t, Dm,   3 * Dm, Ln, (long)3 * Dm * Dm, acc);
        set(1,  enc_wo,   ewo_t,   Dm,   Dm,     Ln, (long)Dm * Dm,     acc);
        set(2,  enc_w1,   ew1_t,   Dm,   DFFm,   Ln, (long)Dm * DFFm,   acc);
        set(3,  enc_w2,   ew2_t,   DFFm, Dm,     Ln, (long)Dm * DFFm,   acc);
        set(4,  dec_wqkv, dwqkv_t, Dm,   3 * Dm, Ln, (long)3 * Dm * Dm, acc);
        set(5,  dec_wq,   dwq_t,   Dm,   Dm,     Ln, (long)Dm * Dm,     acc);
        set(6,  dec_wo,   dwo_t,   Dm,   Dm,     Ln, (long)Dm * Dm,     acc);
        set(7,  dec_wkv,  dwkv_t,  Dm,   2 * Dm, Ln, (long)2 * Dm * Dm, acc);
        set(8,  dec_woc,  dwoc_t,  Dm,   Dm,     Ln, (long)Dm * Dm,     acc);
        set(9,  dec_w1,   dw1_t,   Dm,   DFFm,   Ln, (long)Dm * DFFm,   acc);
        set(10, dec_w2,   dw2_t,   DFFm, Dm,     Ln, (long)Dm * DFFm,   acc);
        set(11, fc_w,     fcw_t,   Dm,   Vm,     1,  (long)Dm * Vm,     acc);
        wcvt_all<<<acc, 256, 0, stream>>>(pk);
    }

    embed_pe<<<dim3(Mrows, 2), 256, 0, stream>>>(
        batch_src, src_emb, X, Xbf, trg, trg_emb, Y, Ybf);

    const long VTs  = (long)16 * DHm * Sn;   // per-layer VT stride (elements)
    const long Osb  = (long)Mrows * Dm;      // split-K partial stride

    // --------------------------------- encoder ----------------------------
    for (int l = 0; l < Ln; ++l) {
        gemm_bf<64,128,4,true,false,false,true,false><<<dim3(12, 32, 1), 256, 0, stream>>>(
            Xbf, ewqkv_t + (size_t)l * 3 * Dm * Dm, QKVbf, nullptr,
            Dm, Dm, Dm, 3 * Dm, 0,0,0,0,0,0, 1, VT, 2 * Dm, 0);
        flash_attn<0><<<dim3(16, 16), 512, 0, stream>>>(
            QKVbf, QKVbf + Dm, VT, AObf, batch_src, 3 * Dm, 3 * Dm);
        gemm_bf<64,64,8,false,false,false,false,false><<<dim3(8, 32, 2), 512, 0, stream>>>(
            AObf, ewo_t + (size_t)l * Dm * Dm, O, nullptr,
            256, Dm, Dm, Dm, 256, 0, 256, 0, Osb, 0, 1, nullptr, 0, 0);
        ln_sum3<<<Mrows, 256, 0, stream>>>(O, O1, X, X,
            enc_ln1s + l * Dm, enc_ln1b + l * Dm, Xbf);
        gemm_bf<64,128,4,true,true,true,false,false><<<dim3(16, 32, 1), 256, 0, stream>>>(
            Xbf, ew1_t + (size_t)l * DFFm * Dm, FHbf, enc_b1 + l * DFFm,
            Dm, Dm, Dm, DFFm, 0,0,0,0,0,0, 1, nullptr, 0, 0);
        gemm_bf<64,64,8,false,true,false,false,false><<<dim3(8, 32, 2), 512, 0, stream>>>(
            FHbf, ew2_t + (size_t)l * Dm * DFFm, O, enc_b2 + l * Dm,
            1024, DFFm, DFFm, Dm, 1024, 0, 1024, 0, Osb, 0, 1, nullptr, 0, 0);
        ln_sum3<<<Mrows, 256, 0, stream>>>(O, O1, X, X,
            enc_ln2s + l * Dm, enc_ln2b + l * Dm, Xbf);
    }

    // all 6 decoder cross-attn KV projections, one batched dispatch (z = layer)
    gemm_bf<64,128,4,true,false,false,true,false><<<dim3(8, 32, Ln), 256, 0, stream>>>(
        Xbf, dwkv_t, KVC, nullptr,
        Dm, Dm, Dm, 2 * Dm,
        0, 0, (long)2 * Dm * Dm, 0, (long)Mrows * 2 * Dm, 0, 1,
        VTC, Dm, VTs);

    // --------------------------------- decoder ----------------------------
    for (int l = 0; l < Ln; ++l) {
        // self-attention (causal)
        gemm_bf<64,128,4,true,false,false,true,false><<<dim3(12, 32, 1), 256, 0, stream>>>(
            Ybf, dwqkv_t + (size_t)l * 3 * Dm * Dm, QKVbf, nullptr,
            Dm, Dm, Dm, 3 * Dm, 0,0,0,0,0,0, 1, VT, 2 * Dm, 0);
        flash_attn<1><<<dim3(16, 16), 512, 0, stream>>>(
            QKVbf, QKVbf + Dm, VT, AObf, nullptr, 3 * Dm, 3 * Dm);
        gemm_bf<64,64,8,false,false,false,false,false><<<dim3(8, 32, 2), 512, 0, stream>>>(
            AObf, dwo_t + (size_t)l * Dm * Dm, O, nullptr,
            256, Dm, Dm, Dm, 256, 0, 256, 0, Osb, 0, 1, nullptr, 0, 0);
        ln_sum3<<<Mrows, 256, 0, stream>>>(O, O1, Y, Y,
            dec_ln1s + l * Dm, dec_ln1b + l * Dm, Ybf);

        // cross-attention (pad mask): qc = post-ln1 y @ wq  (reference-faithful)
        gemm_bf<64,64,8,true,false,false,false,false><<<dim3(8, 32, 1), 512, 0, stream>>>(
            Ybf, dwq_t + (size_t)l * Dm * Dm, QCbf, nullptr,
            Dm, Dm, Dm, Dm, 0,0,0,0,0,0, 1, nullptr, 0, 0);
        flash_attn<0><<<dim3(16, 16), 512, 0, stream>>>(
            QCbf, KVC + (size_t)l * Mrows * 2 * Dm,
            VTC + (size_t)l * VTs, AObf, batch_src, Dm, 2 * Dm);
        gemm_bf<64,64,8,false,false,false,false,false><<<dim3(8, 32, 2), 512, 0, stream>>>(
            AObf, dwoc_t + (size_t)l * Dm * Dm, O, nullptr,
            256, Dm, Dm, Dm, 256, 0, 256, 0, Osb, 0, 1, nullptr, 0, 0);
        ln_sum3<<<Mrows, 256, 0, stream>>>(O, O1, Y, Y,
            dec_ln2s + l * Dm, dec_ln2b + l * Dm, Ybf);

        // feed-forward
        gemm_bf<64,128,4,true,true,true,false,false><<<dim3(16, 32, 1), 256, 0, stream>>>(
            Ybf, dw1_t + (size_t)l * DFFm * Dm, FHbf, dec_b1 + l * DFFm,
            Dm, Dm, Dm, DFFm, 0,0,0,0,0,0, 1, nullptr, 0, 0);
        gemm_bf<64,64,8,false,true,false,false,false><<<dim3(8, 32, 2), 512, 0, stream>>>(
            FHbf, dw2_t + (size_t)l * Dm * DFFm, O, dec_b2 + l * Dm,
            1024, DFFm, DFFm, Dm, 1024, 0, 1024, 0, Osb, 0, 1, nullptr, 0, 0);
        ln_sum3<<<Mrows, 256, 0, stream>>>(O, O1, Y, Y,
            dec_ln3s + l * Dm, dec_ln3b + l * Dm, Ybf);
    }

    // final projection to vocab: 64x128 tile, 3 blocks/CU (12 waves/CU TLP),
    // XCD-swizzled (8000 blocks, 1000/XCD strip, row-tile innermost)
    gemm_bf<64,128,4,false,true,false,false,true><<<dim3(Vm / 128, Mrows / 64, 1), 256, 0, stream>>>(
        Ybf, fcw_t, (float*)d_out, fc_b,
        Dm, Dm, Dm, Vm, 0,0,0,0,0,0, 1, nullptr, 0, 0);
}

// Round 17
// 1427.826 us; speedup vs baseline: 1.0469x; 1.0415x over previous
//
#include <hip/hip_runtime.h>
#include <cmath>

#define Dm   512
#define Hn   8
#define Ln   6
#define DFFm 2048
#define Vm   32000
#define Bn   2
#define Sn   1024
#define DHm  64
#define Mrows (Bn*Sn)   // 2048

typedef unsigned short ushort_t;
typedef __attribute__((ext_vector_type(8))) short          s16x8;
typedef __attribute__((ext_vector_type(8))) unsigned short u16x8;
typedef __attribute__((ext_vector_type(4))) float          f32x4;

__device__ __forceinline__ ushort_t f2bf(float x) {
    union { float f; unsigned u; } un; un.f = x;
    unsigned r = un.u + 0x7fffu + ((un.u >> 16) & 1u);
    return (ushort_t)(r >> 16);
}

// ---------------------------------------------------------------------------
// Stage TR rows x 64 k of bf16 from global into a swizzled LDS tile,
// cooperatively across NW waves (T2 swizzle via pre-swizzled source;
// global_load_lds writes linearly).
// ---------------------------------------------------------------------------
template<int TR, int NW>
__device__ __forceinline__ void stage_tile(const ushort_t* __restrict__ src, int ld,
                                           ushort_t* lds, int k0, int w, int lane)
{
    constexpr int CH = TR / (8 * NW);           // row-chunks per wave
    #pragma unroll
    for (int c = 0; c < CH; ++c) {
        const int rb = (w * CH + c) * 8;        // wave-uniform row base
        const int r  = rb + (lane >> 3);
        const ushort_t* gp = src + (size_t)r * ld + k0
                           + (((lane & 7) ^ ((lane >> 3) & 7)) << 3);
        __builtin_amdgcn_global_load_lds(
            (const __attribute__((address_space(1))) void*)gp,
            (__attribute__((address_space(3))) void*)(lds + rb * 64),
            16, 0, 0);
    }
}

// read 8 bf16: LDS tile row r, logical 16B-slot st (0..7)
__device__ __forceinline__ s16x8 ldrd(const ushort_t* lds, int r, int st)
{
    return *(const s16x8*)&lds[r * 64 + ((st ^ (r & 7)) << 3)];
}

// ---------------------------------------------------------------------------
// bf16 MFMA GEMM: C[M,N] = A[M,K] @ Bt[N,K]^T  (+bias) (+relu)
// Double-buffered LDS, 1-deep prefetch, one barrier per K-step.
// NW: 4 -> 2x2 wave grid; 8 -> 2x4 (512 thr). NW=8 only where blocks/CU is
//   the binding constraint (64x64 GEMMs). fc measured-best: 128^2, NW=4.
// Split-K usage: grid.z=2, nh=1, A_sb=B_sb=K_half, C_sb=partial stride,
//   K=K_half; bias applied only by blockIdx.z==0.
// VTOUT: cols in [voff, voff+512) written transposed to (VTp+z*VT_sz)[zz][d][s].
// SWZ (fc only): XCD-aware bijective remap + nontemporal C stores (logits are
//   write-once; keep L2 for weight panels).
// ---------------------------------------------------------------------------
template<int TM, int TN, int NW, bool OBF, bool BIAS, bool RELU, bool VTOUT, bool SWZ>
__global__ __launch_bounds__(NW * 64) void gemm_bf(
    const ushort_t* __restrict__ A, const ushort_t* __restrict__ Bt,
    void* __restrict__ Cv, const float* __restrict__ bias,
    int K, int lda, int ldb, int ldc,
    long A_sb, long A_sh, long B_sb, long B_sh, long C_sb, long C_sh, int nh,
    ushort_t* __restrict__ VTp, int voff, long VT_sz)
{
    constexpr int WC = NW / 2;                  // wave-grid cols (2 or 4)
    constexpr int FI = TM / 32;                 // frags per wave, M dir
    constexpr int FJ = TN / (16 * WC);          // frags per wave, N dir
    __shared__ __align__(16) ushort_t As[2][TM * 64];
    __shared__ __align__(16) ushort_t Bs[2][TN * 64];

    const int z = blockIdx.z, b = z / nh, h = z - b * nh;
    A  += (size_t)b * A_sb + (size_t)h * A_sh;
    Bt += (size_t)b * B_sb + (size_t)h * B_sh;
    ushort_t* VTl = VTp + (size_t)z * VT_sz;

    int bx = blockIdx.x, by = blockIdx.y;
    if constexpr (SWZ) {
        const int ncol = gridDim.x, nrow = gridDim.y;
        const int total = ncol * nrow;
        const int flat = bx + by * ncol;          // dispatch order (x fastest)
        const int per = total >> 3;
        const int g = (flat & 7) * per + (flat >> 3);
        bx = g / nrow;
        by = g - bx * nrow;
    }

    const int tid  = threadIdx.x;
    const int w    = tid >> 6, lane = tid & 63;
    const int m0   = by * TM, n0 = bx * TN;
    const int rw   = (w / WC) * (TM / 2);       // wave sub-tile row base
    const int cn   = (w % WC) * (TN / WC);      // wave sub-tile col base
    const int l15  = lane & 15, l4 = lane >> 4;

    const ushort_t* Ab = A + (size_t)m0 * lda;
    const ushort_t* Bb = Bt + (size_t)n0 * ldb;

    f32x4 acc[FI][FJ] = {};

    stage_tile<TM, NW>(Ab, lda, As[0], 0, w, lane);
    stage_tile<TN, NW>(Bb, ldb, Bs[0], 0, w, lane);
    __syncthreads();

    const int nk = K >> 6;
    for (int t = 0; t < nk; ++t) {
        const int cur = t & 1;
        if (t + 1 < nk) {
            stage_tile<TM, NW>(Ab, lda, As[cur ^ 1], (t + 1) << 6, w, lane);
            stage_tile<TN, NW>(Bb, ldb, Bs[cur ^ 1], (t + 1) << 6, w, lane);
        }
        #pragma unroll
        for (int ks = 0; ks < 2; ++ks) {
            const int st = ks * 4 + l4;
            s16x8 av[FI], bv[FJ];
            #pragma unroll
            for (int i = 0; i < FI; ++i) av[i] = ldrd(As[cur], rw + i * 16 + l15, st);
            #pragma unroll
            for (int j = 0; j < FJ; ++j) bv[j] = ldrd(Bs[cur], cn + j * 16 + l15, st);
            #pragma unroll
            for (int i = 0; i < FI; ++i)
                #pragma unroll
                for (int j = 0; j < FJ; ++j)
                    acc[i][j] = __builtin_amdgcn_mfma_f32_16x16x32_bf16(
                                    av[i], bv[j], acc[i][j], 0, 0, 0);
        }
        __syncthreads();
    }

    // epilogue: D[col=lane&15, row=(lane>>4)*4 + r]  (m89-verified layout)
    const int colb = n0 + cn + l15;
    const int rowb = m0 + rw + (l4 << 2);
    const bool doBias = BIAS && (blockIdx.z == 0);
    float bvv[FJ];
    #pragma unroll
    for (int j = 0; j < FJ; ++j) bvv[j] = doBias ? bias[colb + j * 16] : 0.f;

    if constexpr (OBF) {
        ushort_t* C = (ushort_t*)Cv + (size_t)b * C_sb + (size_t)h * C_sh;
        #pragma unroll
        for (int i = 0; i < FI; ++i)
            #pragma unroll
            for (int r = 0; r < 4; ++r) {
                const int row = rowb + i * 16 + r;
                #pragma unroll
                for (int j = 0; j < FJ; ++j) {
                    float v = acc[i][j][r] + bvv[j];
                    if (RELU) v = fmaxf(v, 0.f);
                    const int col = colb + j * 16;
                    if (VTOUT && col >= voff && col < voff + 512) {
                        const int hc = (col - voff) >> 6, d = (col - voff) & 63;
                        const int zz = (row >> 10) * 8 + hc;
                        VTl[(size_t)zz * (64 * Sn) + (size_t)d * Sn + (row & (Sn - 1))] = f2bf(v);
                    } else {
                        C[(size_t)row * ldc + col] = f2bf(v);
                    }
                }
            }
    } else {
        float* C = (float*)Cv + (size_t)b * C_sb + (size_t)h * C_sh;
        #pragma unroll
        for (int i = 0; i < FI; ++i)
            #pragma unroll
            for (int r = 0; r < 4; ++r) {
                const size_t row = rowb + i * 16 + r;
                #pragma unroll
                for (int j = 0; j < FJ; ++j) {
                    float v = acc[i][j][r] + bvv[j];
                    if (RELU) v = fmaxf(v, 0.f);
                    if (SWZ) __builtin_nontemporal_store(v, &C[row * ldc + colb + j * 16]);
                    else     C[row * ldc + colb + j * 16] = v;
                }
            }
    }
}

// ---------------------------------------------------------------------------
// Flash-fused attention, KV-split across 2 wave groups (8 waves, 512 thr).
// MODE 0: pad mask; MODE 1: causal. (See round-10 notes.)
// ---------------------------------------------------------------------------
template<int MODE>
__global__ __launch_bounds__(512) void flash_attn(
    const ushort_t* __restrict__ Qp, const ushort_t* __restrict__ Kp,
    const ushort_t* __restrict__ VTp, ushort_t* __restrict__ AO,
    const int* __restrict__ tok, int ldq, int ldk)
{
    __shared__ __align__(16) ushort_t Ks[2][2][64 * 64];   // [group][buf]
    __shared__ __align__(16) ushort_t Vs[2][2][64 * 64];
    __shared__ __align__(16) ushort_t Ps[8][16 * 64];
    __shared__ float msk[Sn];
    __shared__ float mrg[4][64][25];   // group-1 partials: 16 o + 4 m + 4 l

    const int z = blockIdx.y, b = z >> 3, h = z & 7;
    const int qb = blockIdx.x * 64;
    const int tid = threadIdx.x, w = tid >> 6, lane = tid & 63;
    const int g = w >> 2, w4 = w & 3;
    const int l15 = lane & 15, l4 = lane >> 4;

    const ushort_t* Qbase = Qp + (size_t)b * Sn * ldq + h * 64;
    const ushort_t* Kbase = Kp + (size_t)b * Sn * ldk + h * 64;
    const ushort_t* Vbase = VTp + (size_t)z * 64 * Sn;
    ushort_t* Obase = AO + ((size_t)(b * Sn + qb)) * Dm + h * 64;

    if (MODE == 0) {
        const int* tb = tok + (size_t)b * Sn;
        for (int i = tid; i < Sn; i += 512) msk[i] = (tb[i] == 0) ? 1.f : 0.f;
    }

    const int qrow = qb + w4 * 16 + l15;
    s16x8 qv[2];
    qv[0] = *(const s16x8*)(Qbase + (size_t)qrow * ldq + l4 * 8);
    qv[1] = *(const s16x8*)(Qbase + (size_t)qrow * ldq + 32 + l4 * 8);

    f32x4 o[4] = {};
    float m[4], lsum[4];
    #pragma unroll
    for (int r = 0; r < 4; ++r) { m[r] = -1e30f; lsum[r] = 0.f; }

    const int nt = (MODE == 1) ? (qb / 64 + 1) : (Sn / 64);
    const int nIt = (nt + 1) >> 1;

    if (g < nt) {
        stage_tile<64, 4>(Kbase + (size_t)(g * 64) * ldk, ldk, Ks[g][0], 0, w4, lane);
        stage_tile<64, 4>(Vbase, Sn, Vs[g][0], g * 64, w4, lane);
    }
    __syncthreads();

    for (int it = 0; it < nIt; ++it) {
        const int kt = 2 * it + g;
        const int cur = it & 1;
        if (kt + 2 < nt) {
            stage_tile<64, 4>(Kbase + (size_t)((kt + 2) * 64) * ldk, ldk, Ks[g][cur ^ 1], 0, w4, lane);
            stage_tile<64, 4>(Vbase, Sn, Vs[g][cur ^ 1], (kt + 2) * 64, w4, lane);
        }
        if (kt < nt) {
            f32x4 s[4] = {};
            #pragma unroll
            for (int ks = 0; ks < 2; ++ks) {
                const int st = ks * 4 + l4;
                #pragma unroll
                for (int j = 0; j < 4; ++j) {
                    s16x8 bv = ldrd(Ks[g][cur], j * 16 + l15, st);
                    s[j] = __builtin_amdgcn_mfma_f32_16x16x32_bf16(qv[ks], bv, s[j], 0, 0, 0);
                }
            }

            #pragma unroll
            for (int j = 0; j < 4; ++j) {
                const int col = kt * 64 + j * 16 + l15;
                #pragma unroll
                for (int r = 0; r < 4; ++r) {
                    float v = s[j][r] * 0.125f;
                    if (MODE == 0) { if (msk[col] != 0.f) v = -1e9f; }
                    else           { if (col > qb + w4 * 16 + l4 * 4 + r) v = -1e9f; }
                    s[j][r] = v;
                }
            }

            float mt[4];
            #pragma unroll
            for (int r = 0; r < 4; ++r)
                mt[r] = fmaxf(fmaxf(s[0][r], s[1][r]), fmaxf(s[2][r], s[3][r]));
            #pragma unroll
            for (int mk = 1; mk < 16; mk <<= 1)
                #pragma unroll
                for (int r = 0; r < 4; ++r)
                    mt[r] = fmaxf(mt[r], __shfl_xor(mt[r], mk));

            float al[4];
            #pragma unroll
            for (int r = 0; r < 4; ++r) {
                const float mn = fmaxf(m[r], mt[r]);
                al[r] = __expf(m[r] - mn);
                m[r] = mn;
            }

            float rs[4] = {0.f, 0.f, 0.f, 0.f};
            ushort_t* pw = Ps[w];
            #pragma unroll
            for (int j = 0; j < 4; ++j) {
                const int slot = j * 2 + (l15 >> 3), e = l15 & 7;
                #pragma unroll
                for (int r = 0; r < 4; ++r) {
                    const float pvv = __expf(s[j][r] - m[r]);
                    rs[r] += pvv;
                    const int row = l4 * 4 + r;
                    pw[row * 64 + ((slot ^ (row & 7)) << 3) + e] = f2bf(pvv);
                }
            }
            #pragma unroll
            for (int mk = 1; mk < 16; mk <<= 1)
                #pragma unroll
                for (int r = 0; r < 4; ++r)
                    rs[r] += __shfl_xor(rs[r], mk);
            #pragma unroll
            for (int r = 0; r < 4; ++r) lsum[r] = lsum[r] * al[r] + rs[r];

            #pragma unroll
            for (int jd = 0; jd < 4; ++jd)
                #pragma unroll
                for (int r = 0; r < 4; ++r)
                    o[jd][r] *= al[r];
            #pragma unroll
            for (int ks2 = 0; ks2 < 2; ++ks2) {
                const int st2 = ks2 * 4 + l4;
                s16x8 pa = ldrd(pw, l15, st2);
                #pragma unroll
                for (int jd = 0; jd < 4; ++jd) {
                    s16x8 bv2 = ldrd(Vs[g][cur], jd * 16 + l15, st2);
                    o[jd] = __builtin_amdgcn_mfma_f32_16x16x32_bf16(pa, bv2, o[jd], 0, 0, 0);
                }
            }
        }
        __syncthreads();
    }

    // ---- merge group 1 into group 0, then write ----
    if (g == 1) {
        float* mp = mrg[w4][lane];
        #pragma unroll
        for (int jd = 0; jd < 4; ++jd)
            #pragma unroll
            for (int r = 0; r < 4; ++r)
                mp[jd * 4 + r] = o[jd][r];
        #pragma unroll
        for (int r = 0; r < 4; ++r) { mp[16 + r] = m[r]; mp[20 + r] = lsum[r]; }
    }
    __syncthreads();
    if (g == 0) {
        const float* mp = mrg[w4][lane];
        float a0[4], a1[4], inv[4];
        #pragma unroll
        for (int r = 0; r < 4; ++r) {
            const float m1 = mp[16 + r];
            const float mm = fmaxf(m[r], m1);
            a0[r] = __expf(m[r] - mm);
            a1[r] = __expf(m1 - mm);
            inv[r] = 1.f / (lsum[r] * a0[r] + mp[20 + r] * a1[r]);
        }
        #pragma unroll
        for (int jd = 0; jd < 4; ++jd)
            #pragma unroll
            for (int r = 0; r < 4; ++r)
                Obase[(size_t)(w4 * 16 + l4 * 4 + r) * Dm + jd * 16 + l15] =
                    f2bf((o[jd][r] * a0[r] + mp[jd * 4 + r] * a1[r]) * inv[r]);
    }
}

// ---------------------------------------------------------------------------
// Merged weight transpose+cvt: 12 weight groups, one dispatch.
// dls = per-layer stride of dst.
// ---------------------------------------------------------------------------
struct WEnt { const float* src; ushort_t* dst; int R, C, tile0; long dls; };
struct WPack { WEnt e[12]; };

__global__ __launch_bounds__(256) void wcvt_all(WPack p)
{
    const int bid = blockIdx.x;
    int i = 0;
    #pragma unroll
    for (int k = 1; k < 12; ++k) if (bid >= p.e[k].tile0) i = k;
    const WEnt wd = p.e[i];
    const int rel = bid - wd.tile0;
    const int tC = wd.C >> 5, tR = wd.R >> 5;
    const int tpl = tC * tR;
    const int l = rel / tpl, t2 = rel - l * tpl;
    const int ty = t2 / tC, tx = t2 - ty * tC;

    const float* in  = wd.src + (size_t)l * wd.R * wd.C;
    ushort_t*    out = wd.dst + (size_t)l * wd.dls;

    __shared__ float tbuf[32][33];
    const int r0 = ty * 32, c0 = tx * 32;
    const int tid = threadIdx.x;
    const int r = tid >> 5, c = tid & 31;
    #pragma unroll
    for (int q = 0; q < 4; ++q)
        tbuf[r + q * 8][c] = in[(size_t)(r0 + r + q * 8) * wd.C + c0 + c];
    __syncthreads();
    const int c2 = tid >> 5, r2 = tid & 31;
    #pragma unroll
    for (int q = 0; q < 4; ++q)
        out[(size_t)(c0 + c2 + q * 8) * wd.R + r0 + r2] = f2bf(tbuf[r2][c2 + q * 8]);
}

// ---------------------------------------------------------------------------
// x = layernorm(s0 + s1 + xres)*g + b  (s0,s1 = split-K partials).
// Writes fp32 x (in-place ok: xres may alias x) and bf16 xbf.
// ---------------------------------------------------------------------------
__global__ __launch_bounds__(256) void ln_sum3(
    const float* __restrict__ s0, const float* __restrict__ s1,
    const float* __restrict__ xres, float* __restrict__ x,
    const float* __restrict__ gam, const float* __restrict__ bet,
    ushort_t* __restrict__ xbf)
{
    const long row = blockIdx.x;
    const int t = threadIdx.x;
    const long base = row * Dm;
    float v0 = s0[base + t]       + s1[base + t]       + xres[base + t];
    float v1 = s0[base + t + 256] + s1[base + t + 256] + xres[base + t + 256];

    float sum = v0 + v1, ssq = v0 * v0 + v1 * v1;
    __shared__ float red[8];
    for (int off = 32; off; off >>= 1) {
        sum += __shfl_down(sum, off);
        ssq += __shfl_down(ssq, off);
    }
    const int lane = t & 63, w = t >> 6;
    if (lane == 0) { red[w] = sum; red[4 + w] = ssq; }
    __syncthreads();
    sum = red[0] + red[1] + red[2] + red[3];
    ssq = red[4] + red[5] + red[6] + red[7];

    const float mean = sum * (1.f / Dm);
    const float var  = ssq * (1.f / Dm) - mean * mean;
    const float r = rsqrtf(var + 1e-5f);
    const float r0 = (v0 - mean) * r * gam[t] + bet[t];
    const float r1 = (v1 - mean) * r * gam[t + 256] + bet[t + 256];
    x[base + t] = r0; x[base + t + 256] = r1;
    xbf[base + t] = f2bf(r0);
    xbf[base + t + 256] = f2bf(r1);
}

// ---------------------------------------------------------------------------
// Embeddings for both streams in one dispatch: grid.y 0 -> src, 1 -> trg.
// ---------------------------------------------------------------------------
__global__ __launch_bounds__(256) void embed_pe(
    const int* __restrict__ tokA, const float* __restrict__ embA,
    float* __restrict__ outA, ushort_t* __restrict__ outbfA,
    const int* __restrict__ tokB, const float* __restrict__ embB,
    float* __restrict__ outB, ushort_t* __restrict__ outbfB)
{
    const int bs = blockIdx.x;
    const int s = bs % Sn;
    const int t = threadIdx.x;
    const int*      tok   = blockIdx.y ? tokB : tokA;
    const float*    emb   = blockIdx.y ? embB : embA;
    float*          out   = blockIdx.y ? outB : outA;
    ushort_t*       outbf = blockIdx.y ? outbfB : outbfA;
    const int token = tok[bs];
    #pragma unroll
    for (int r = 0; r < 2; ++r) {
        const int d = t + r * 256;
        const int i = d & ~1;
        const float ang = (float)s * powf(10000.0f, -(float)i / (float)Dm);
        const float pe = (d & 1) ? cosf(ang) : sinf(ang);
        const float v = emb[(size_t)token * Dm + d] * 22.627416997969522f + pe;
        out[(size_t)bs * Dm + d] = v;
        outbf[(size_t)bs * Dm + d] = f2bf(v);
    }
}

// ---------------------------------------------------------------------------
extern "C" void kernel_launch(void* const* d_in, const int* in_sizes, int n_in,
                              void* d_out, int out_size, void* d_ws, size_t ws_size,
                              hipStream_t stream)
{
    const int*   batch_src = (const int*)d_in[0];
    const int*   trg       = (const int*)d_in[1];
    const float* src_emb   = (const float*)d_in[2];
    const float* trg_emb   = (const float*)d_in[3];
    const float* fc_w      = (const float*)d_in[4];
    const float* fc_b      = (const float*)d_in[5];
    const float* enc_wqkv  = (const float*)d_in[6];
    const float* enc_wo    = (const float*)d_in[7];
    const float* enc_ln1s  = (const float*)d_in[8];
    const float* enc_ln1b  = (const float*)d_in[9];
    const float* enc_w1    = (const float*)d_in[10];
    const float* enc_b1    = (const float*)d_in[11];
    const float* enc_w2    = (const float*)d_in[12];
    const float* enc_b2    = (const float*)d_in[13];
    const float* enc_ln2s  = (const float*)d_in[14];
    const float* enc_ln2b  = (const float*)d_in[15];
    const float* dec_wqkv  = (const float*)d_in[16];
    const float* dec_wo    = (const float*)d_in[17];
    const float* dec_ln1s  = (const float*)d_in[18];
    const float* dec_ln1b  = (const float*)d_in[19];
    const float* dec_wq    = (const float*)d_in[20];
    const float* dec_wkv   = (const float*)d_in[21];
    const float* dec_woc   = (const float*)d_in[22];
    const float* dec_ln2s  = (const float*)d_in[23];
    const float* dec_ln2b  = (const float*)d_in[24];
    const float* dec_w1    = (const float*)d_in[25];
    const float* dec_b1    = (const float*)d_in[26];
    const float* dec_w2    = (const float*)d_in[27];
    const float* dec_b2    = (const float*)d_in[28];
    const float* dec_ln3s  = (const float*)d_in[29];
    const float* dec_ln3b  = (const float*)d_in[30];
    (void)in_sizes; (void)n_in; (void)out_size; (void)ws_size;

    char* p = (char*)d_ws;
    auto alloc = [&](size_t bytes) { char* r = p; p += (bytes + 255) & ~(size_t)255; return r; };
    float*    X     = (float*)alloc((size_t)Mrows * Dm * 4);
    float*    Y     = (float*)alloc((size_t)Mrows * Dm * 4);
    float*    O     = (float*)alloc((size_t)2 * Mrows * Dm * 4);   // split-K partials
    float*    O1    = O + (size_t)Mrows * Dm;
    ushort_t* Xbf   = (ushort_t*)alloc((size_t)Mrows * Dm * 2);
    ushort_t* Ybf   = (ushort_t*)alloc((size_t)Mrows * Dm * 2);
    ushort_t* QKVbf = (ushort_t*)alloc((size_t)Mrows * 3 * Dm * 2);
    ushort_t* QCbf  = (ushort_t*)alloc((size_t)Mrows * Dm * 2);
    ushort_t* AObf  = (ushort_t*)alloc((size_t)Mrows * Dm * 2);
    ushort_t* FHbf  = (ushort_t*)alloc((size_t)Mrows * DFFm * 2);
    ushort_t* VT    = (ushort_t*)alloc((size_t)16 * DHm * Sn * 2);
    ushort_t* KVC   = (ushort_t*)alloc((size_t)Ln * Mrows * 2 * Dm * 2);
    ushort_t* VTC   = (ushort_t*)alloc((size_t)Ln * 16 * DHm * Sn * 2);
    ushort_t* ewqkv_t = (ushort_t*)alloc((size_t)Ln * 3 * Dm * Dm * 2);
    ushort_t* ewo_t   = (ushort_t*)alloc((size_t)Ln * Dm * Dm * 2);
    ushort_t* ew1_t   = (ushort_t*)alloc((size_t)Ln * DFFm * Dm * 2);
    ushort_t* ew2_t   = (ushort_t*)alloc((size_t)Ln * Dm * DFFm * 2);
    ushort_t* dwqkv_t = (ushort_t*)alloc((size_t)Ln * 3 * Dm * Dm * 2);
    ushort_t* dwq_t   = (ushort_t*)alloc((size_t)Ln * Dm * Dm * 2);
    ushort_t* dwo_t   = (ushort_t*)alloc((size_t)Ln * Dm * Dm * 2);
    ushort_t* dwkv_t  = (ushort_t*)alloc((size_t)Ln * 2 * Dm * Dm * 2);
    ushort_t* dwoc_t  = (ushort_t*)alloc((size_t)Ln * Dm * Dm * 2);
    ushort_t* dw1_t   = (ushort_t*)alloc((size_t)Ln * DFFm * Dm * 2);
    ushort_t* dw2_t   = (ushort_t*)alloc((size_t)Ln * Dm * DFFm * 2);
    ushort_t* fcw_t   = (ushort_t*)alloc((size_t)Vm * Dm * 2);

    // ---------------- merged weight transpose+cvt (one dispatch) ----------
    {
        WPack pk;
        auto set = [&](int i, const float* s, ushort_t* d, int R, int C, int nl,
                       long dls, int& acc) {
            pk.e[i] = { s, d, R, C, acc, dls };
            acc += (R >> 5) * (C >> 5) * nl;
        };
        int acc = 0;
        set(0,  enc_wqkv, ewqkv_t, Dm,   3 * Dm, Ln, (long)3 * Dm * Dm, acc);
        set(1,  enc_wo,   ewo_t,   Dm,   Dm,     Ln, (long)Dm * Dm,     acc);
        set(2,  enc_w1,   ew1_t,   Dm,   DFFm,   Ln, (long)Dm * DFFm,   acc);
        set(3,  enc_w2,   ew2_t,   DFFm, Dm,     Ln, (long)Dm * DFFm,   acc);
        set(4,  dec_wqkv, dwqkv_t, Dm,   3 * Dm, Ln, (long)3 * Dm * Dm, acc);
        set(5,  dec_wq,   dwq_t,   Dm,   Dm,     Ln, (long)Dm * Dm,     acc);
        set(6,  dec_wo,   dwo_t,   Dm,   Dm,     Ln, (long)Dm * Dm,     acc);
        set(7,  dec_wkv,  dwkv_t,  Dm,   2 * Dm, Ln, (long)2 * Dm * Dm, acc);
        set(8,  dec_woc,  dwoc_t,  Dm,   Dm,     Ln, (long)Dm * Dm,     acc);
        set(9,  dec_w1,   dw1_t,   Dm,   DFFm,   Ln, (long)Dm * DFFm,   acc);
        set(10, dec_w2,   dw2_t,   DFFm, Dm,     Ln, (long)Dm * DFFm,   acc);
        set(11, fc_w,     fcw_t,   Dm,   Vm,     1,  (long)Dm * Vm,     acc);
        wcvt_all<<<acc, 256, 0, stream>>>(pk);
    }

    embed_pe<<<dim3(Mrows, 2), 256, 0, stream>>>(
        batch_src, src_emb, X, Xbf, trg, trg_emb, Y, Ybf);

    const long VTs  = (long)16 * DHm * Sn;   // per-layer VT stride (elements)
    const long Osb  = (long)Mrows * Dm;      // split-K partial stride

    // --------------------------------- encoder ----------------------------
    for (int l = 0; l < Ln; ++l) {
        gemm_bf<64,128,4,true,false,false,true,false><<<dim3(12, 32, 1), 256, 0, stream>>>(
            Xbf, ewqkv_t + (size_t)l * 3 * Dm * Dm, QKVbf, nullptr,
            Dm, Dm, Dm, 3 * Dm, 0,0,0,0,0,0, 1, VT, 2 * Dm, 0);
        flash_attn<0><<<dim3(16, 16), 512, 0, stream>>>(
            QKVbf, QKVbf + Dm, VT, AObf, batch_src, 3 * Dm, 3 * Dm);
        gemm_bf<64,64,8,false,false,false,false,false><<<dim3(8, 32, 2), 512, 0, stream>>>(
            AObf, ewo_t + (size_t)l * Dm * Dm, O, nullptr,
            256, Dm, Dm, Dm, 256, 0, 256, 0, Osb, 0, 1, nullptr, 0, 0);
        ln_sum3<<<Mrows, 256, 0, stream>>>(O, O1, X, X,
            enc_ln1s + l * Dm, enc_ln1b + l * Dm, Xbf);
        gemm_bf<64,128,4,true,true,true,false,false><<<dim3(16, 32, 1), 256, 0, stream>>>(
            Xbf, ew1_t + (size_t)l * DFFm * Dm, FHbf, enc_b1 + l * DFFm,
            Dm, Dm, Dm, DFFm, 0,0,0,0,0,0, 1, nullptr, 0, 0);
        gemm_bf<64,64,8,false,true,false,false,false><<<dim3(8, 32, 2), 512, 0, stream>>>(
            FHbf, ew2_t + (size_t)l * Dm * DFFm, O, enc_b2 + l * Dm,
            1024, DFFm, DFFm, Dm, 1024, 0, 1024, 0, Osb, 0, 1, nullptr, 0, 0);
        ln_sum3<<<Mrows, 256, 0, stream>>>(O, O1, X, X,
            enc_ln2s + l * Dm, enc_ln2b + l * Dm, Xbf);
    }

    // all 6 decoder cross-attn KV projections, one batched dispatch (z = layer)
    gemm_bf<64,128,4,true,false,false,true,false><<<dim3(8, 32, Ln), 256, 0, stream>>>(
        Xbf, dwkv_t, KVC, nullptr,
        Dm, Dm, Dm, 2 * Dm,
        0, 0, (long)2 * Dm * Dm, 0, (long)Mrows * 2 * Dm, 0, 1,
        VTC, Dm, VTs);

    // --------------------------------- decoder ----------------------------
    for (int l = 0; l < Ln; ++l) {
        // self-attention (causal)
        gemm_bf<64,128,4,true,false,false,true,false><<<dim3(12, 32, 1), 256, 0, stream>>>(
            Ybf, dwqkv_t + (size_t)l * 3 * Dm * Dm, QKVbf, nullptr,
            Dm, Dm, Dm, 3 * Dm, 0,0,0,0,0,0, 1, VT, 2 * Dm, 0);
        flash_attn<1><<<dim3(16, 16), 512, 0, stream>>>(
            QKVbf, QKVbf + Dm, VT, AObf, nullptr, 3 * Dm, 3 * Dm);
        gemm_bf<64,64,8,false,false,false,false,false><<<dim3(8, 32, 2), 512, 0, stream>>>(
            AObf, dwo_t + (size_t)l * Dm * Dm, O, nullptr,
            256, Dm, Dm, Dm, 256, 0, 256, 0, Osb, 0, 1, nullptr, 0, 0);
        ln_sum3<<<Mrows, 256, 0, stream>>>(O, O1, Y, Y,
            dec_ln1s + l * Dm, dec_ln1b + l * Dm, Ybf);

        // cross-attention (pad mask): qc = post-ln1 y @ wq  (reference-faithful)
        gemm_bf<64,64,8,true,false,false,false,false><<<dim3(8, 32, 1), 512, 0, stream>>>(
            Ybf, dwq_t + (size_t)l * Dm * Dm, QCbf, nullptr,
            Dm, Dm, Dm, Dm, 0,0,0,0,0,0, 1, nullptr, 0, 0);
        flash_attn<0><<<dim3(16, 16), 512, 0, stream>>>(
            QCbf, KVC + (size_t)l * Mrows * 2 * Dm,
            VTC + (size_t)l * VTs, AObf, batch_src, Dm, 2 * Dm);
        gemm_bf<64,64,8,false,false,false,false,false><<<dim3(8, 32, 2), 512, 0, stream>>>(
            AObf, dwoc_t + (size_t)l * Dm * Dm, O, nullptr,
            256, Dm, Dm, Dm, 256, 0, 256, 0, Osb, 0, 1, nullptr, 0, 0);
        ln_sum3<<<Mrows, 256, 0, stream>>>(O, O1, Y, Y,
            dec_ln2s + l * Dm, dec_ln2b + l * Dm, Ybf);

        // feed-forward
        gemm_bf<64,128,4,true,true,true,false,false><<<dim3(16, 32, 1), 256, 0, stream>>>(
            Ybf, dw1_t + (size_t)l * DFFm * Dm, FHbf, dec_b1 + l * DFFm,
            Dm, Dm, Dm, DFFm, 0,0,0,0,0,0, 1, nullptr, 0, 0);
        gemm_bf<64,64,8,false,true,false,false,false><<<dim3(8, 32, 2), 512, 0, stream>>>(
            FHbf, dw2_t + (size_t)l * Dm * DFFm, O, dec_b2 + l * Dm,
            1024, DFFm, DFFm, Dm, 1024, 0, 1024, 0, Osb, 0, 1, nullptr, 0, 0);
        ln_sum3<<<Mrows, 256, 0, stream>>>(O, O1, Y, Y,
            dec_ln3s + l * Dm, dec_ln3b + l * Dm, Ybf);
    }

    // final projection to vocab: 128^2, NW=4 (measured best), XCD-swizzled,
    // nontemporal logits store (write-once stream; keep L2 for weights)
    gemm_bf<128,128,4,false,true,false,false,true><<<dim3(Vm / 128, 16, 1), 256, 0, stream>>>(
        Ybf, fcw_t, (float*)d_out, fc_b,
        Dm, Dm, Dm, Vm, 0,0,0,0,0,0, 1, nullptr, 0, 0);
}